// Round 7
// baseline (173.379 us; speedup 1.0000x reference)
//
#include <hip/hip_runtime.h>
#include <hip/hip_bf16.h>
#include <math.h>

constexpr int SEQ   = 512;
constexpr int HIDC  = 1024;
constexpr int NH    = 16;
constexpr int HDIM  = 64;
constexpr int NFREQ = 33;   // rfft bins for n=64
constexpr int NFP   = 128;  // padded packed spectral length (66 -> 128, zero pad)

typedef unsigned short u16;
typedef __bf16 bf16x8 __attribute__((ext_vector_type(8)));
typedef float  f32x4  __attribute__((ext_vector_type(4)));
typedef unsigned short u16x8 __attribute__((ext_vector_type(8)));

typedef __attribute__((address_space(3))) void       as3_void;
typedef __attribute__((address_space(1))) const void as1_void;

// async global->LDS, 16B per lane; LDS dest = wave-uniform base + lane*16
__device__ __forceinline__ void gload16(const u16* g, u16* l) {
    __builtin_amdgcn_global_load_lds((as1_void*)g, (as3_void*)l, 16, 0, 0);
}

// dtype-agnostic input load: f32 ? float : bf16
__device__ __forceinline__ float ldin(const void* p, int i, int f32) {
    if (f32) return ((const float*)p)[i];
    return __bfloat162float(((const __hip_bfloat16*)p)[i]);
}

__device__ __forceinline__ u16 f2b(float f) {   // RNE fp32 -> bf16 bits
    unsigned int u = __builtin_bit_cast(unsigned int, f);
    u += 0x7fffu + ((u >> 16) & 1u);
    return (u16)(u >> 16);
}
__device__ __forceinline__ float b2f(u16 b) {
    return __builtin_bit_cast(float, (unsigned int)b << 16);
}
// fp32 -> (hi, lo) bf16 pair; hi + lo ~ f to ~16 mantissa bits
__device__ __forceinline__ void split2(float f, u16& hi, u16& lo) {
    hi = f2b(f);
    lo = f2b(f - b2f(hi));
}

// inline dtype sniff: wave-uniform, no barrier. bf16 weights have small
// exponents; fp32 seen as bf16 halves shows ~half with exp >= 134.
__device__ __forceinline__ int sniffF(const u16* wq) {
    const int lane = threadIdx.x & 63;
    const ushort4 a = *(const ushort4*)(wq + lane * 8);
    const ushort4 b = *(const ushort4*)(wq + lane * 8 + 4);
    int bad = 0;
    {
        const u16 vs[8] = {a.x, a.y, a.z, a.w, b.x, b.y, b.z, b.w};
        #pragma unroll
        for (int j = 0; j < 8; ++j)
            if (((vs[j] >> 7) & 0xFF) >= 134) bad++;
    }
    #pragma unroll
    for (int off = 32; off > 0; off >>= 1) bad += __shfl_xor(bad, off, 64);
    return (bad > 32) ? 1 : 0;
}

// ---------------- K1a: prep = W transpose+split (z<4) | x split (z==4) ----------------
__global__ __launch_bounds__(256) void prep_kernel(
    const void* __restrict__ W0, const void* __restrict__ W1,
    const void* __restrict__ W2, const void* __restrict__ W3,
    u16* __restrict__ H0, u16* __restrict__ L0,
    u16* __restrict__ H1, u16* __restrict__ L1,
    u16* __restrict__ H2, u16* __restrict__ L2,
    u16* __restrict__ H3, u16* __restrict__ L3,
    const void* __restrict__ xsrc, u16* __restrict__ xhi, u16* __restrict__ xlo)
{
    const int F  = sniffF((const u16*)W0);
    const int mz = blockIdx.z;

    if (mz == 4) {   // x split: 256 blocks x 256 thr x 8 elems
        const int blk = blockIdx.y * 16 + blockIdx.x;
        const int i0  = blk * 2048 + threadIdx.x * 8;
        #pragma unroll
        for (int g = 0; g < 2; ++g) {
            const int i = i0 + g * 4;
            float v[4];
            if (F) {
                const float4 f = *(const float4*)((const float*)xsrc + i);
                v[0] = f.x; v[1] = f.y; v[2] = f.z; v[3] = f.w;
            } else {
                #pragma unroll
                for (int j = 0; j < 4; ++j) v[j] = ldin(xsrc, i + j, 0);
            }
            ushort4 oh, ol;
            u16 h, l;
            split2(v[0], h, l); oh.x = h; ol.x = l;
            split2(v[1], h, l); oh.y = h; ol.y = l;
            split2(v[2], h, l); oh.z = h; ol.z = l;
            split2(v[3], h, l); oh.w = h; ol.w = l;
            *(ushort4*)&xhi[i] = oh;
            *(ushort4*)&xlo[i] = ol;
        }
        return;
    }

    __shared__ float t[64][65];
    const void* W = (mz == 0) ? W0 : (mz == 1) ? W1 : (mz == 2) ? W2 : W3;
    u16* H = (mz == 0) ? H0 : (mz == 1) ? H1 : (mz == 2) ? H2 : H3;
    u16* L = (mz == 0) ? L0 : (mz == 1) ? L1 : (mz == 2) ? L2 : L3;
    const int n0 = blockIdx.x * 64, k0 = blockIdx.y * 64;
    const int tid = threadIdx.x;

    #pragma unroll
    for (int i = 0; i < 4; ++i) {
        const int item = i * 256 + tid;
        const int r = item >> 4, c4 = (item & 15) * 4;
        if (F) {
            const float4 v = *(const float4*)((const float*)W + (k0 + r) * HIDC + n0 + c4);
            t[r][c4 + 0] = v.x; t[r][c4 + 1] = v.y; t[r][c4 + 2] = v.z; t[r][c4 + 3] = v.w;
        } else {
            #pragma unroll
            for (int j = 0; j < 4; ++j)
                t[r][c4 + j] = ldin(W, (k0 + r) * HIDC + n0 + c4 + j, 0);
        }
    }
    __syncthreads();
    #pragma unroll
    for (int i = 0; i < 4; ++i) {
        const int item = i * 256 + tid;
        const int r = item >> 4, c4 = (item & 15) * 4;   // r: n-offset, c4: k-offset
        ushort4 oh, ol;
        u16 h, l;
        split2(t[c4 + 0][r], h, l); oh.x = h; ol.x = l;
        split2(t[c4 + 1][r], h, l); oh.y = h; ol.y = l;
        split2(t[c4 + 2][r], h, l); oh.z = h; ol.z = l;
        split2(t[c4 + 3][r], h, l); oh.w = h; ol.w = l;
        *(ushort4*)&H[(n0 + r) * HIDC + k0 + c4] = oh;
        *(ushort4*)&L[(n0 + r) * HIDC + k0 + c4] = ol;
    }
}

// ---------------- K1c: 3-term split-bf16 MFMA GEMM (+ fused DFT epilogue) ----------------
// MODE 0 (MT=64): QKV; grid (24,8).
//   mat 0/1 (Q,K): epilogue computes per-head rfft + amplitude-normalize + pad
//     + split directly into Qs/Ks (spectra). Tile = 64 s-rows x 2 full heads.
//   mat 2 (V): transposed split store into VT [h*64+d][s].
// MODE 1 (MT=32): O-proj; grid (8,16). Out: Y fp32 = acc + bias + residual.
template <int MODE, int MT>
__global__ __launch_bounds__(256) void mfma3_gemm_kernel(
    const u16* __restrict__ Ahi, const u16* __restrict__ Alo,
    const u16* __restrict__ B0h, const u16* __restrict__ B0l,
    const u16* __restrict__ B1h, const u16* __restrict__ B1l,
    const u16* __restrict__ B2h, const u16* __restrict__ B2l,
    const void* __restrict__ b0, const void* __restrict__ b1, const void* __restrict__ b2,
    const void* __restrict__ xres,
    u16* __restrict__ Qsh, u16* __restrict__ Qsl,
    u16* __restrict__ Ksh, u16* __restrict__ Ksl,
    u16* __restrict__ Vth, u16* __restrict__ Vtl,
    float* __restrict__ Yout,
    const void* __restrict__ wq_sniff)
{
    constexpr int NMI = MT / 16;        // acc row tiles
    constexpr int NAC = MT / 32;        // A chunks per wave
    constexpr int ACH = MT * 64;        // A hi region (u16)
    constexpr int BUF = 2 * ACH + 16384;
    __shared__ __align__(16) u16 smem[2 * BUF];
    __shared__ float tcs[64], tsn[64];

    const int F    = sniffF((const u16*)wq_sniff);
    const int tid  = threadIdx.x;
    const int lane = tid & 63, wv = tid >> 6;
    const int q15 = lane & 15, hi = lane >> 4, l7 = lane & 7;
    const int hi4 = hi * 4;
    const int m0 = blockIdx.y * MT;
    const int n0 = blockIdx.x * 128;

    const u16 *Bh, *Bl; const void* bias; int col0, mat = 0;
    if (MODE == 0) {
        mat  = n0 >> 10;
        col0 = n0 & 1023;
        Bh   = (mat == 0) ? B0h : (mat == 1) ? B1h : B2h;
        Bl   = (mat == 0) ? B0l : (mat == 1) ? B1l : B2l;
        bias = (mat == 0) ? b0  : (mat == 1) ? b1  : b2;
    } else {
        col0 = n0; Bh = B0h; Bl = B0l; bias = b0;
    }

    const int rsub = lane >> 3;
    const int gsw  = ((lane & 7) ^ rsub) * 8;
    const u16* pAh[2]; const u16* pAl[2];
    const u16* pBh[4]; const u16* pBl[4];
    int dA[2], dB[4];
    #pragma unroll
    for (int j = 0; j < NAC; ++j) {
        const int c = wv * NAC + j;
        pAh[j] = Ahi + (m0 + c * 8 + rsub) * HIDC + gsw;
        pAl[j] = Alo + (m0 + c * 8 + rsub) * HIDC + gsw;
        dA[j]  = c * 512;
    }
    #pragma unroll
    for (int j = 0; j < 4; ++j) {
        const int c = wv * 4 + j;
        pBh[j] = Bh + (col0 + c * 8 + rsub) * HIDC + gsw;
        pBl[j] = Bl + (col0 + c * 8 + rsub) * HIDC + gsw;
        dB[j]  = c * 512;
    }

    int g16[2];
    #pragma unroll
    for (int kc = 0; kc < 2; ++kc) g16[kc] = (((kc * 4) + hi) ^ l7) * 8;
    int afo[4], bfo[2];
    #pragma unroll
    for (int mi = 0; mi < NMI; ++mi) afo[mi] = (mi * 16 + q15) * 64;
    #pragma unroll
    for (int ni = 0; ni < 2; ++ni) bfo[ni] = (wv * 32 + ni * 16 + q15) * 64;

    f32x4 acc[NMI][2];
    #pragma unroll
    for (int mi = 0; mi < NMI; ++mi)
        #pragma unroll
        for (int ni = 0; ni < 2; ++ni) acc[mi][ni] = f32x4{0.f, 0.f, 0.f, 0.f};

    #pragma unroll
    for (int j = 0; j < NAC; ++j) {
        gload16(pAh[j], smem + dA[j]);
        gload16(pAl[j], smem + ACH + dA[j]);
    }
    #pragma unroll
    for (int j = 0; j < 4; ++j) {
        gload16(pBh[j], smem + 2 * ACH + dB[j]);
        gload16(pBl[j], smem + 2 * ACH + 8192 + dB[j]);
    }
    __syncthreads();

    for (int t = 0; t < 16; ++t) {
        const int bo = (t & 1) * BUF;
        if (t < 15) {
            const int bn = BUF - bo;
            const int k  = (t + 1) * 64;
            #pragma unroll
            for (int j = 0; j < NAC; ++j) {
                gload16(pAh[j] + k, smem + bn + dA[j]);
                gload16(pAl[j] + k, smem + bn + ACH + dA[j]);
            }
            #pragma unroll
            for (int j = 0; j < 4; ++j) {
                gload16(pBh[j] + k, smem + bn + 2 * ACH + dB[j]);
                gload16(pBl[j] + k, smem + bn + 2 * ACH + 8192 + dB[j]);
            }
        }
        #pragma unroll
        for (int kc = 0; kc < 2; ++kc) {
            bf16x8 ah[NMI], al[NMI], bh2[2], bl2[2];
            #pragma unroll
            for (int mi = 0; mi < NMI; ++mi) {
                ah[mi] = *(const bf16x8*)(smem + bo +       afo[mi] + g16[kc]);
                al[mi] = *(const bf16x8*)(smem + bo + ACH + afo[mi] + g16[kc]);
            }
            #pragma unroll
            for (int ni = 0; ni < 2; ++ni) {
                bh2[ni] = *(const bf16x8*)(smem + bo + 2 * ACH +        bfo[ni] + g16[kc]);
                bl2[ni] = *(const bf16x8*)(smem + bo + 2 * ACH + 8192 + bfo[ni] + g16[kc]);
            }
            #pragma unroll
            for (int mi = 0; mi < NMI; ++mi)
                #pragma unroll
                for (int ni = 0; ni < 2; ++ni) {
                    acc[mi][ni] = __builtin_amdgcn_mfma_f32_16x16x32_bf16(
                        ah[mi], bh2[ni], acc[mi][ni], 0, 0, 0);
                    acc[mi][ni] = __builtin_amdgcn_mfma_f32_16x16x32_bf16(
                        ah[mi], bl2[ni], acc[mi][ni], 0, 0, 0);
                    acc[mi][ni] = __builtin_amdgcn_mfma_f32_16x16x32_bf16(
                        al[mi], bh2[ni], acc[mi][ni], 0, 0, 0);
                }
        }
        __syncthreads();
    }

    if (MODE == 1) {
        // O-proj epilogue: Y = acc + bias + residual
        #pragma unroll
        for (int ni = 0; ni < 2; ++ni) {
            const int col = col0 + wv * 32 + ni * 16 + q15;
            const float bval = ldin(bias, col, F);
            #pragma unroll
            for (int mi = 0; mi < NMI; ++mi) {
                const int row0 = m0 + mi * 16 + hi4;
                #pragma unroll
                for (int r = 0; r < 4; ++r) {
                    const int row = row0 + r;
                    Yout[row * HIDC + col] =
                        acc[mi][ni][r] + bval + ldin(xres, row * HIDC + col, F);
                }
            }
        }
    } else if (mat == 2) {
        // V epilogue: transposed split store VT[col][row]
        #pragma unroll
        for (int ni = 0; ni < 2; ++ni) {
            const int col = col0 + wv * 32 + ni * 16 + q15;
            const float bval = ldin(bias, col, F);
            #pragma unroll
            for (int mi = 0; mi < NMI; ++mi) {
                const int row0 = m0 + mi * 16 + hi4;
                ushort4 oh, ol;
                u16 h_, l_;
                split2(acc[mi][ni][0] + bval, h_, l_); oh.x = h_; ol.x = l_;
                split2(acc[mi][ni][1] + bval, h_, l_); oh.y = h_; ol.y = l_;
                split2(acc[mi][ni][2] + bval, h_, l_); oh.z = h_; ol.z = l_;
                split2(acc[mi][ni][3] + bval, h_, l_); oh.w = h_; ol.w = l_;
                *(ushort4*)&Vth[col * SEQ + row0] = oh;
                *(ushort4*)&Vtl[col * SEQ + row0] = ol;
            }
        }
    } else {
        // ---- fused DFT epilogue (Q or K): tile = 64 s-rows x 2 heads ----
        float* Cf = (float*)smem;                 // [64][128] f32 (aliases buf0)
        #pragma unroll
        for (int ni = 0; ni < 2; ++ni) {
            const int c = wv * 32 + ni * 16 + q15;
            const float bval = ldin(bias, col0 + c, F);
            #pragma unroll
            for (int mi = 0; mi < NMI; ++mi)
                #pragma unroll
                for (int r = 0; r < 4; ++r)
                    Cf[(mi * 16 + hi4 + r) * 128 + c] = acc[mi][ni][r] + bval;
        }
        if (tid < 64) {
            float sv, cv;
            sincosf((float)tid * (6.283185307179586f / 64.0f), &sv, &cv);
            tcs[tid] = cv; tsn[tid] = sv;
        }
        __syncthreads();

        // D fragments (head-independent): col c<33 -> cos, c<66 -> -sin, else 0
        bf16x8 Dh[2][2], Dl[2][2];
        #pragma unroll
        for (int ni = 0; ni < 2; ++ni) {
            const int c = wv * 32 + ni * 16 + q15;
            #pragma unroll
            for (int kc = 0; kc < 2; ++kc) {
                u16x8 bh_, bl_;
                #pragma unroll
                for (int e = 0; e < 8; ++e) {
                    const int k = (kc * 4 + hi) * 8 + e;
                    float dv;
                    if (c < 33)      dv = tcs[(c * k) & 63];
                    else if (c < 66) dv = -tsn[((c - 33) * k) & 63];
                    else             dv = 0.0f;
                    u16 h_, l_;
                    split2(dv, h_, l_);
                    bh_[e] = h_; bl_[e] = l_;
                }
                Dh[ni][kc] = __builtin_bit_cast(bf16x8, bh_);
                Dl[ni][kc] = __builtin_bit_cast(bf16x8, bl_);
            }
        }

        u16* AH = smem + 16384;                   // [64][64] bf16 hi (swizzled)
        u16* AL = smem + 20480;                   // [64][64] bf16 lo
        float* C2 = (float*)(smem + 24576);       // [64][128] f32 spectra
        u16* Oh = (mat == 0) ? Qsh : Ksh;
        u16* Ol = (mat == 0) ? Qsl : Ksl;

        #pragma unroll
        for (int head = 0; head < 2; ++head) {
            const int hh = (col0 >> 6) + head;
            {   // stage A split with the gload-equivalent granule XOR swizzle:
                // AH[row][d] = Cf[row][head*64 + ((d>>3)^(row&7))*8 + (d&7)]
                const int row = tid >> 2;
                const int d0  = (tid & 3) * 16;
                const int rx  = row & 7;
                #pragma unroll
                for (int d = d0; d < d0 + 16; ++d) {
                    const int src = (((d >> 3) ^ rx) * 8) + (d & 7);
                    u16 h_, l_;
                    split2(Cf[row * 128 + head * 64 + src], h_, l_);
                    AH[row * 64 + d] = h_;
                    AL[row * 64 + d] = l_;
                }
            }
            __syncthreads();
            f32x4 a2[4][2];
            #pragma unroll
            for (int mi = 0; mi < 4; ++mi)
                #pragma unroll
                for (int ni = 0; ni < 2; ++ni) a2[mi][ni] = f32x4{0.f, 0.f, 0.f, 0.f};
            #pragma unroll
            for (int kc = 0; kc < 2; ++kc) {
                const int g = g16[kc];
                bf16x8 ah2[4], al2[4];
                #pragma unroll
                for (int mi = 0; mi < 4; ++mi) {
                    ah2[mi] = *(const bf16x8*)(AH + (mi * 16 + q15) * 64 + g);
                    al2[mi] = *(const bf16x8*)(AL + (mi * 16 + q15) * 64 + g);
                }
                #pragma unroll
                for (int mi = 0; mi < 4; ++mi)
                    #pragma unroll
                    for (int ni = 0; ni < 2; ++ni) {
                        a2[mi][ni] = __builtin_amdgcn_mfma_f32_16x16x32_bf16(
                            ah2[mi], Dh[ni][kc], a2[mi][ni], 0, 0, 0);
                        a2[mi][ni] = __builtin_amdgcn_mfma_f32_16x16x32_bf16(
                            ah2[mi], Dl[ni][kc], a2[mi][ni], 0, 0, 0);
                        a2[mi][ni] = __builtin_amdgcn_mfma_f32_16x16x32_bf16(
                            al2[mi], Dh[ni][kc], a2[mi][ni], 0, 0, 0);
                    }
            }
            __syncthreads();   // AH/AL reads done; order vs C2 writes
            #pragma unroll
            for (int mi = 0; mi < 4; ++mi)
                #pragma unroll
                for (int ni = 0; ni < 2; ++ni)
                    #pragma unroll
                    for (int r = 0; r < 4; ++r)
                        C2[(mi * 16 + hi4 + r) * 128 + wv * 32 + ni * 16 + q15] = a2[mi][ni][r];
            __syncthreads();
            {   // normalize + split + pad; 4 threads/row, 32 f each
                const int row = tid >> 2, tf = tid & 3;
                u16 vh[32], vl[32];
                #pragma unroll
                for (int j = 0; j < 32; ++j) {
                    const int f = tf * 32 + j;
                    float val = 0.0f;
                    if (f < 66) {
                        const int fb = (f < 33) ? f : (f - 33);
                        const float re = C2[row * 128 + fb];
                        const float im = C2[row * 128 + 33 + fb];
                        const float a  = sqrtf(re * re + im * im);
                        const float sc = (a > 0.0f) ? rsqrtf(a) : 0.0f;
                        val = ((f < 33) ? re : im) * sc;
                    }
                    split2(val, vh[j], vl[j]);
                }
                const int obase = (hh * SEQ + m0 + row) * NFP + tf * 32;
                #pragma unroll
                for (int j4 = 0; j4 < 8; ++j4) {
                    ushort4 oh, ol;
                    oh.x = vh[j4 * 4 + 0]; oh.y = vh[j4 * 4 + 1];
                    oh.z = vh[j4 * 4 + 2]; oh.w = vh[j4 * 4 + 3];
                    ol.x = vl[j4 * 4 + 0]; ol.y = vl[j4 * 4 + 1];
                    ol.z = vl[j4 * 4 + 2]; ol.w = vl[j4 * 4 + 3];
                    *(ushort4*)&Oh[obase + j4 * 4] = oh;
                    *(ushort4*)&Ol[obase + j4 * 4] = ol;
                }
            }
        }
    }
}

// ---------------- K3: MFMA attention (unchanged, verified) ----------------
__global__ __launch_bounds__(128) void attn_mfma_kernel(
    const u16* __restrict__ Qsh, const u16* __restrict__ Qsl,
    const u16* __restrict__ Ksh, const u16* __restrict__ Ksl,
    const u16* __restrict__ VTh, const u16* __restrict__ VTl,
    const int* __restrict__ mask, const void* __restrict__ temp_p,
    u16* __restrict__ chi, u16* __restrict__ clo,
    const void* __restrict__ wq_sniff)
{
    __shared__ __align__(16) u16 smem[32768];   // 64 KB: wave w owns [w*16384, +16384)
    __shared__ int   mask_lds[512];
    __shared__ float mpart[2][16], lpart[2][16], l_final[16];

    const int F    = sniffF((const u16*)wq_sniff);
    const int tid  = threadIdx.x;
    const int lane = tid & 63, w = tid >> 6;
    const int hi = lane >> 4, q15 = lane & 15, l7 = lane & 7;
    const int h  = blockIdx.y, q0 = blockIdx.x * 16;
    const int k0 = w * 256;                     // wave's k-half
    const int WB = w * 16384;                   // wave's LDS region (u16)
    const float temp = ldin(temp_p, 0, F);

    *(int4*)&mask_lds[tid * 4] = *(const int4*)&mask[tid * 4];

    bf16x8 qfh[3], qfl[3];
    {
        const int qrow = (h * SEQ + q0 + q15) * NFP;
        #pragma unroll
        for (int kc = 0; kc < 3; ++kc) {
            qfh[kc] = *(const bf16x8*)(Qsh + qrow + kc * 32 + hi * 8);
            qfl[kc] = *(const bf16x8*)(Qsl + qrow + kc * 32 + hi * 8);
        }
    }

    const int rc4 = lane >> 4;

    auto stageK = [&](int kt, int b) {
        const int base = WB + b * 8192;
        #pragma unroll
        for (int j = 0; j < 8; ++j) {
            const int row = j * 4 + rc4;
            const int gs  = (q15 ^ (row & 7)) * 8;
            const int so  = (h * SEQ + k0 + kt * 32 + row) * NFP + gs;
            gload16(Ksh + so, smem + base + j * 512);
            gload16(Ksl + so, smem + base + 4096 + j * 512);
        }
    };
    auto stageV = [&](int c, int b) {
        const int base = WB + b * 4096;
        #pragma unroll
        for (int j = 0; j < 4; ++j) {
            const int d  = j * 16 + (lane >> 2);
            const int gs = ((lane & 3) ^ (d & 3)) * 8;
            const int so = (h * HDIM + d) * SEQ + k0 + c * 32 + gs;
            gload16(VTh + so, smem + base + j * 512);
            gload16(VTl + so, smem + base + 2048 + j * 512);
        }
    };

    f32x4 sT[16];
    #pragma unroll
    for (int t = 0; t < 16; ++t) sT[t] = f32x4{0.f, 0.f, 0.f, 0.f};

    stageK(0, 0);
    #pragma unroll
    for (int kt = 0; kt < 8; ++kt) {
        if (kt < 7) {
            stageK(kt + 1, (kt + 1) & 1);
            asm volatile("s_waitcnt vmcnt(16)" ::: "memory");
        } else {
            asm volatile("s_waitcnt vmcnt(0)" ::: "memory");
        }
        __builtin_amdgcn_sched_barrier(0);
        const int base = WB + (kt & 1) * 8192;
        #pragma unroll
        for (int tt = 0; tt < 2; ++tt) {
            #pragma unroll
            for (int kc = 0; kc < 3; ++kc) {
                const int ro = (tt * 16 + q15) * 128 + (((kc * 4 + hi) ^ l7) * 8);
                const bf16x8 ah = *(const bf16x8*)(smem + base + ro);
                const bf16x8 al = *(const bf16x8*)(smem + base + 4096 + ro);
                sT[kt * 2 + tt] = __builtin_amdgcn_mfma_f32_16x16x32_bf16(ah, qfh[kc], sT[kt * 2 + tt], 0, 0, 0);
                sT[kt * 2 + tt] = __builtin_amdgcn_mfma_f32_16x16x32_bf16(ah, qfl[kc], sT[kt * 2 + tt], 0, 0, 0);
                sT[kt * 2 + tt] = __builtin_amdgcn_mfma_f32_16x16x32_bf16(al, qfh[kc], sT[kt * 2 + tt], 0, 0, 0);
            }
        }
    }

    __builtin_amdgcn_sched_barrier(0);
    stageV(0, 0);

    float m = -1e30f;
    #pragma unroll
    for (int t = 0; t < 16; ++t) {
        const int4 mv = *(const int4*)&mask_lds[k0 + t * 16 + hi * 4];
        float s;
        s = (mv.x == 0) ? -1e9f : sT[t][0] * temp; sT[t][0] = s; m = fmaxf(m, s);
        s = (mv.y == 0) ? -1e9f : sT[t][1] * temp; sT[t][1] = s; m = fmaxf(m, s);
        s = (mv.z == 0) ? -1e9f : sT[t][2] * temp; sT[t][2] = s; m = fmaxf(m, s);
        s = (mv.w == 0) ? -1e9f : sT[t][3] * temp; sT[t][3] = s; m = fmaxf(m, s);
    }
    m = fmaxf(m, __shfl_xor(m, 16, 64));
    m = fmaxf(m, __shfl_xor(m, 32, 64));
    if (lane < 16) mpart[w][q15] = m;
    __syncthreads();
    const float gm = fmaxf(mpart[0][q15], mpart[1][q15]);
    float sum = 0.0f;
    #pragma unroll
    for (int t = 0; t < 16; ++t) {
        #pragma unroll
        for (int r = 0; r < 4; ++r) {
            const float p = __expf(sT[t][r] - gm);
            sT[t][r] = p;
            sum += p;
        }
    }
    sum += __shfl_xor(sum, 16, 64);
    sum += __shfl_xor(sum, 32, 64);
    if (lane < 16) lpart[w][q15] = sum;
    __syncthreads();
    if (tid < 16) l_final[tid] = lpart[0][tid] + lpart[1][tid];

    const int PH = WB + 8192, PL = PH + 640;
    f32x4 acc[4];
    #pragma unroll
    for (int dt = 0; dt < 4; ++dt) acc[dt] = f32x4{0.f, 0.f, 0.f, 0.f};

    #pragma unroll
    for (int c = 0; c < 8; ++c) {
        if (c < 7) {
            stageV(c + 1, (c + 1) & 1);
            asm volatile("s_waitcnt vmcnt(8)" ::: "memory");
        } else {
            asm volatile("s_waitcnt vmcnt(0)" ::: "memory");
        }
        __builtin_amdgcn_sched_barrier(0);
        #pragma unroll
        for (int tt = 0; tt < 2; ++tt) {
            const int t = c * 2 + tt;
            ushort4 ph, pl;
            u16 hh, ll;
            split2(sT[t][0], hh, ll); ph.x = hh; pl.x = ll;
            split2(sT[t][1], hh, ll); ph.y = hh; pl.y = ll;
            split2(sT[t][2], hh, ll); ph.z = hh; pl.z = ll;
            split2(sT[t][3], hh, ll); ph.w = hh; pl.w = ll;
            const int g  = tt * 2 + (hi >> 1);
            const int po = q15 * 40 + ((g ^ (q15 & 3)) * 8) + (hi & 1) * 4;
            *(ushort4*)(smem + PH + po) = ph;
            *(ushort4*)(smem + PL + po) = pl;
        }
        const int vb  = WB + (c & 1) * 4096;
        const int pro = q15 * 40 + ((hi ^ (q15 & 3)) * 8);
        const bf16x8 pfh = *(const bf16x8*)(smem + PH + pro);
        const bf16x8 pfl = *(const bf16x8*)(smem + PL + pro);
        #pragma unroll
        for (int dt = 0; dt < 4; ++dt) {
            const int vo = (dt * 16 + q15) * 32 + ((hi ^ (q15 & 3)) * 8);
            const bf16x8 vfh = *(const bf16x8*)(smem + vb + vo);
            const bf16x8 vfl = *(const bf16x8*)(smem + vb + 2048 + vo);
            acc[dt] = __builtin_amdgcn_mfma_f32_16x16x32_bf16(pfh, vfh, acc[dt], 0, 0, 0);
            acc[dt] = __builtin_amdgcn_mfma_f32_16x16x32_bf16(pfl, vfh, acc[dt], 0, 0, 0);
            acc[dt] = __builtin_amdgcn_mfma_f32_16x16x32_bf16(pfh, vfl, acc[dt], 0, 0, 0);
        }
    }

    float* pacc = (float*)(smem + WB + 12288);
    #pragma unroll
    for (int dt = 0; dt < 4; ++dt)
        *(f32x4*)&pacc[(dt * 64 + lane) * 4] = acc[dt];
    __syncthreads();
    const float* pa0 = (const float*)(smem + 12288);
    const float* pa1 = (const float*)(smem + 16384 + 12288);
    #pragma unroll
    for (int dd = 0; dd < 2; ++dd) {
        const int dt = w * 2 + dd;
        #pragma unroll
        for (int r = 0; r < 4; ++r) {
            const int idx = (dt * 64 + lane) * 4 + r;
            const float v = (pa0[idx] + pa1[idx]) / l_final[hi * 4 + r];
            u16 hh, ll;
            split2(v, hh, ll);
            const int row = q0 + hi * 4 + r;
            const int col = h * HDIM + dt * 16 + q15;
            chi[row * HIDC + col] = hh;
            clo[row * HIDC + col] = ll;
        }
    }
}

// ---------------- K5: LayerNorm -> out ----------------
__global__ __launch_bounds__(256) void ln_kernel(
    const float* __restrict__ Y, const void* __restrict__ gamma,
    const void* __restrict__ beta, void* __restrict__ out,
    const void* __restrict__ wq_sniff)
{
    const int F = sniffF((const u16*)wq_sniff);
    const int row = blockIdx.x, tid = threadIdx.x;
    float v[4];
    float s = 0.0f, s2 = 0.0f;
    #pragma unroll
    for (int j = 0; j < 4; ++j) {
        v[j] = Y[row * HIDC + tid + j * 256];
        s += v[j]; s2 += v[j] * v[j];
    }
    #pragma unroll
    for (int off = 32; off > 0; off >>= 1) {
        s  += __shfl_xor(s, off, 64);
        s2 += __shfl_xor(s2, off, 64);
    }
    __shared__ float wred[4][2];
    const int w = tid >> 6;
    if ((tid & 63) == 0) { wred[w][0] = s; wred[w][1] = s2; }
    __syncthreads();
    s  = wred[0][0] + wred[1][0] + wred[2][0] + wred[3][0];
    s2 = wred[0][1] + wred[1][1] + wred[2][1] + wred[3][1];
    const float mu   = s / (float)HIDC;
    const float var  = s2 / (float)HIDC - mu * mu;
    const float rstd = rsqrtf(var + 1e-5f);
    #pragma unroll
    for (int j = 0; j < 4; ++j) {
        const int c = tid + j * 256;
        const float g = ldin(gamma, c, F), b = ldin(beta, c, F);
        const float r = (v[j] - mu) * rstd * g + b;
        if (F) ((float*)out)[row * HIDC + c] = r;
        else   ((__hip_bfloat16*)out)[row * HIDC + c] = __float2bfloat16(r);
    }
}

extern "C" void kernel_launch(void* const* d_in, const int* in_sizes, int n_in,
                              void* d_out, int out_size, void* d_ws, size_t ws_size,
                              hipStream_t stream) {
    const void* x    = d_in[0];
    const int*  mask = (const int*)d_in[1];
    const void* Wq   = d_in[2];
    const void* bq   = d_in[3];
    const void* Wk   = d_in[4];
    const void* bk   = d_in[5];
    const void* Wv   = d_in[6];
    const void* bv   = d_in[7];
    const void* Wo   = d_in[8];
    const void* bo   = d_in[9];
    const void* temp = d_in[10];
    const void* gam  = d_in[11];
    const void* bet  = d_in[12];

    float* Y    = (float*)d_ws;              // 512*1024 f32
    u16*   xhi  = (u16*)(Y + SEQ * HIDC);    // each 512*1024 u16
    u16*   xlo  = xhi + SEQ * HIDC;
    u16*   chi  = xlo + SEQ * HIDC;
    u16*   clo  = chi + SEQ * HIDC;
    u16*   VTh  = clo + SEQ * HIDC;          // [h*64+d][s]
    u16*   VTl  = VTh + NH * HDIM * SEQ;
    u16*   Wqh  = VTl + NH * HDIM * SEQ;     // 8 x 1024*1024
    u16*   Wql  = Wqh + HIDC * HIDC;
    u16*   Wkh  = Wql + HIDC * HIDC;
    u16*   Wkl  = Wkh + HIDC * HIDC;
    u16*   Wvh  = Wkl + HIDC * HIDC;
    u16*   Wvl  = Wvh + HIDC * HIDC;
    u16*   Woh  = Wvl + HIDC * HIDC;
    u16*   Wol  = Woh + HIDC * HIDC;
    u16*   Qsh  = Wol + HIDC * HIDC;         // 4 x 16*512*128
    u16*   Qsl  = Qsh + NH * SEQ * NFP;
    u16*   Ksh  = Qsl + NH * SEQ * NFP;
    u16*   Ksl  = Ksh + NH * SEQ * NFP;

    // prep: W transpose+split (z<4) + x split (z==4); dtype sniffed inline
    prep_kernel<<<dim3(16, 16, 5), 256, 0, stream>>>(
        Wq, Wk, Wv, Wo, Wqh, Wql, Wkh, Wkl, Wvh, Wvl, Woh, Wol,
        x, xhi, xlo);

    // QKV projection + fused DFT: Q,K -> spectra; V -> transposed split bf16
    mfma3_gemm_kernel<0, 64><<<dim3(24, 8), 256, 0, stream>>>(
        xhi, xlo, Wqh, Wql, Wkh, Wkl, Wvh, Wvl,
        bq, bk, bv, nullptr,
        Qsh, Qsl, Ksh, Ksl, VTh, VTl, nullptr, Wq);

    // attention (MFMA, k-split + counted-vmcnt dbuf), writes split ctx
    attn_mfma_kernel<<<dim3(SEQ / 16, NH), 128, 0, stream>>>(
        Qsh, Qsl, Ksh, Ksl, VTh, VTl, mask, temp, chi, clo, Wq);

    // O-projection (+bias+residual), MT=32 for 128-block occupancy
    mfma3_gemm_kernel<1, 32><<<dim3(8, 16), 256, 0, stream>>>(
        chi, clo, Woh, Wol, nullptr, nullptr, nullptr, nullptr,
        bo, nullptr, nullptr, x,
        nullptr, nullptr, nullptr, nullptr, nullptr, nullptr, Y, Wq);

    ln_kernel<<<SEQ, 256, 0, stream>>>(Y, gam, bet, d_out, Wq);
}

// Round 8
// 155.718 us; speedup vs baseline: 1.1134x; 1.1134x over previous
//
#include <hip/hip_runtime.h>
#include <hip/hip_bf16.h>
#include <math.h>

constexpr int SEQ   = 512;
constexpr int HIDC  = 1024;
constexpr int NH    = 16;
constexpr int HDIM  = 64;
constexpr int NFREQ = 33;   // rfft bins for n=64
constexpr int NFP   = 128;  // padded packed spectral length (66 -> 128, zero pad)

typedef unsigned short u16;
typedef __bf16 bf16x8 __attribute__((ext_vector_type(8)));
typedef float  f32x4  __attribute__((ext_vector_type(4)));
typedef unsigned short u16x8 __attribute__((ext_vector_type(8)));

typedef __attribute__((address_space(3))) void       as3_void;
typedef __attribute__((address_space(1))) const void as1_void;

// async global->LDS, 16B per lane; LDS dest = wave-uniform base + lane*16
__device__ __forceinline__ void gload16(const u16* g, u16* l) {
    __builtin_amdgcn_global_load_lds((as1_void*)g, (as3_void*)l, 16, 0, 0);
}

// dtype-agnostic input load: f32 ? float : bf16
__device__ __forceinline__ float ldin(const void* p, int i, int f32) {
    if (f32) return ((const float*)p)[i];
    return __bfloat162float(((const __hip_bfloat16*)p)[i]);
}

__device__ __forceinline__ u16 f2b(float f) {   // RNE fp32 -> bf16 bits
    unsigned int u = __builtin_bit_cast(unsigned int, f);
    u += 0x7fffu + ((u >> 16) & 1u);
    return (u16)(u >> 16);
}
__device__ __forceinline__ float b2f(u16 b) {
    return __builtin_bit_cast(float, (unsigned int)b << 16);
}
// fp32 -> (hi, lo) bf16 pair; hi + lo ~ f to ~16 mantissa bits
__device__ __forceinline__ void split2(float f, u16& hi, u16& lo) {
    hi = f2b(f);
    lo = f2b(f - b2f(hi));
}

// inline dtype sniff: wave-uniform, no barrier.
__device__ __forceinline__ int sniffF(const u16* wq) {
    const int lane = threadIdx.x & 63;
    const ushort4 a = *(const ushort4*)(wq + lane * 8);
    const ushort4 b = *(const ushort4*)(wq + lane * 8 + 4);
    int bad = 0;
    {
        const u16 vs[8] = {a.x, a.y, a.z, a.w, b.x, b.y, b.z, b.w};
        #pragma unroll
        for (int j = 0; j < 8; ++j)
            if (((vs[j] >> 7) & 0xFF) >= 134) bad++;
    }
    #pragma unroll
    for (int off = 32; off > 0; off >>= 1) bad += __shfl_xor(bad, off, 64);
    return (bad > 32) ? 1 : 0;
}

// ---------------- K1a: prep = W transpose+split (z<4) | x split (z==4) ----------------
__global__ __launch_bounds__(256) void prep_kernel(
    const void* __restrict__ W0, const void* __restrict__ W1,
    const void* __restrict__ W2, const void* __restrict__ W3,
    u16* __restrict__ H0, u16* __restrict__ L0,
    u16* __restrict__ H1, u16* __restrict__ L1,
    u16* __restrict__ H2, u16* __restrict__ L2,
    u16* __restrict__ H3, u16* __restrict__ L3,
    const void* __restrict__ xsrc, u16* __restrict__ xhi, u16* __restrict__ xlo)
{
    const int F  = sniffF((const u16*)W0);
    const int mz = blockIdx.z;

    if (mz == 4) {   // x split
        const int blk = blockIdx.y * 16 + blockIdx.x;
        const int i0  = blk * 2048 + threadIdx.x * 8;
        #pragma unroll
        for (int g = 0; g < 2; ++g) {
            const int i = i0 + g * 4;
            float v[4];
            if (F) {
                const float4 f = *(const float4*)((const float*)xsrc + i);
                v[0] = f.x; v[1] = f.y; v[2] = f.z; v[3] = f.w;
            } else {
                #pragma unroll
                for (int j = 0; j < 4; ++j) v[j] = ldin(xsrc, i + j, 0);
            }
            ushort4 oh, ol;
            u16 h, l;
            split2(v[0], h, l); oh.x = h; ol.x = l;
            split2(v[1], h, l); oh.y = h; ol.y = l;
            split2(v[2], h, l); oh.z = h; ol.z = l;
            split2(v[3], h, l); oh.w = h; ol.w = l;
            *(ushort4*)&xhi[i] = oh;
            *(ushort4*)&xlo[i] = ol;
        }
        return;
    }

    __shared__ float t[64][65];
    const void* W = (mz == 0) ? W0 : (mz == 1) ? W1 : (mz == 2) ? W2 : W3;
    u16* H = (mz == 0) ? H0 : (mz == 1) ? H1 : (mz == 2) ? H2 : H3;
    u16* L = (mz == 0) ? L0 : (mz == 1) ? L1 : (mz == 2) ? L2 : L3;
    const int n0 = blockIdx.x * 64, k0 = blockIdx.y * 64;
    const int tid = threadIdx.x;

    #pragma unroll
    for (int i = 0; i < 4; ++i) {
        const int item = i * 256 + tid;
        const int r = item >> 4, c4 = (item & 15) * 4;
        if (F) {
            const float4 v = *(const float4*)((const float*)W + (k0 + r) * HIDC + n0 + c4);
            t[r][c4 + 0] = v.x; t[r][c4 + 1] = v.y; t[r][c4 + 2] = v.z; t[r][c4 + 3] = v.w;
        } else {
            #pragma unroll
            for (int j = 0; j < 4; ++j)
                t[r][c4 + j] = ldin(W, (k0 + r) * HIDC + n0 + c4 + j, 0);
        }
    }
    __syncthreads();
    #pragma unroll
    for (int i = 0; i < 4; ++i) {
        const int item = i * 256 + tid;
        const int r = item >> 4, c4 = (item & 15) * 4;   // r: n-offset, c4: k-offset
        ushort4 oh, ol;
        u16 h, l;
        split2(t[c4 + 0][r], h, l); oh.x = h; ol.x = l;
        split2(t[c4 + 1][r], h, l); oh.y = h; ol.y = l;
        split2(t[c4 + 2][r], h, l); oh.z = h; ol.z = l;
        split2(t[c4 + 3][r], h, l); oh.w = h; ol.w = l;
        *(ushort4*)&H[(n0 + r) * HIDC + k0 + c4] = oh;
        *(ushort4*)&L[(n0 + r) * HIDC + k0 + c4] = ol;
    }
}

// ---------------- K1c: 3-term split-bf16 MFMA GEMM, N-tile 64 ----------------
// MODE 0 (MT=64): QKV; grid (48,8): bx<16 -> Q, <32 -> K, <48 -> V.
//   Q/K: split store to Qm/Km [s][1024] hi/lo. V: transposed split [h*64+d][s].
// MODE 1 (MT=32): O-proj; grid (16,16). Out: Y fp32 = acc + bias + residual.
// LDS/block: MODE0 64KB (2 blocks/CU), MODE1 48KB (3 blocks/CU).
template <int MODE, int MT>
__global__ __launch_bounds__(256) void mfma3_gemm_kernel(
    const u16* __restrict__ Ahi, const u16* __restrict__ Alo,
    const u16* __restrict__ B0h, const u16* __restrict__ B0l,
    const u16* __restrict__ B1h, const u16* __restrict__ B1l,
    const u16* __restrict__ B2h, const u16* __restrict__ B2l,
    const void* __restrict__ b0, const void* __restrict__ b1, const void* __restrict__ b2,
    const void* __restrict__ xres,
    u16* __restrict__ Qh, u16* __restrict__ Ql,
    u16* __restrict__ Kh, u16* __restrict__ Kl,
    u16* __restrict__ Vth, u16* __restrict__ Vtl,
    float* __restrict__ Yout,
    const void* __restrict__ wq_sniff)
{
    constexpr int NMI = MT / 16;        // acc row tiles
    constexpr int NAC = MT / 32;        // A chunks per wave
    constexpr int ACH = MT * 64;        // A hi region (u16)
    constexpr int BUF = 2 * ACH + 8192; // + B hi/lo (64 rows x 64)
    __shared__ __align__(16) u16 smem[2 * BUF];

    const int F    = sniffF((const u16*)wq_sniff);
    const int tid  = threadIdx.x;
    const int lane = tid & 63, wv = tid >> 6;
    const int q15 = lane & 15, hi = lane >> 4, l7 = lane & 7;
    const int hi4 = hi * 4;
    const int m0 = blockIdx.y * MT;
    const int n0 = blockIdx.x * 64;

    const u16 *Bh, *Bl; const void* bias; int col0, mat = 0;
    if (MODE == 0) {
        mat  = n0 >> 10;
        col0 = n0 & 1023;
        Bh   = (mat == 0) ? B0h : (mat == 1) ? B1h : B2h;
        Bl   = (mat == 0) ? B0l : (mat == 1) ? B1l : B2l;
        bias = (mat == 0) ? b0  : (mat == 1) ? b1  : b2;
    } else {
        col0 = n0; Bh = B0h; Bl = B0l; bias = b0;
    }

    const int rsub = lane >> 3;
    const int gsw  = ((lane & 7) ^ rsub) * 8;
    const u16* pAh[2]; const u16* pAl[2];
    const u16* pBh[2]; const u16* pBl[2];
    int dA[2], dB[2];
    #pragma unroll
    for (int j = 0; j < NAC; ++j) {
        const int c = wv * NAC + j;
        pAh[j] = Ahi + (m0 + c * 8 + rsub) * HIDC + gsw;
        pAl[j] = Alo + (m0 + c * 8 + rsub) * HIDC + gsw;
        dA[j]  = c * 512;
    }
    #pragma unroll
    for (int j = 0; j < 2; ++j) {
        const int c = wv * 2 + j;
        pBh[j] = Bh + (col0 + c * 8 + rsub) * HIDC + gsw;
        pBl[j] = Bl + (col0 + c * 8 + rsub) * HIDC + gsw;
        dB[j]  = c * 512;
    }

    int g16[2];
    #pragma unroll
    for (int kc = 0; kc < 2; ++kc) g16[kc] = (((kc * 4) + hi) ^ l7) * 8;
    int afo[4];
    #pragma unroll
    for (int mi = 0; mi < NMI; ++mi) afo[mi] = (mi * 16 + q15) * 64;
    const int bfo = (wv * 16 + q15) * 64;

    f32x4 acc[NMI];
    #pragma unroll
    for (int mi = 0; mi < NMI; ++mi) acc[mi] = f32x4{0.f, 0.f, 0.f, 0.f};

    #pragma unroll
    for (int j = 0; j < NAC; ++j) {
        gload16(pAh[j], smem + dA[j]);
        gload16(pAl[j], smem + ACH + dA[j]);
    }
    #pragma unroll
    for (int j = 0; j < 2; ++j) {
        gload16(pBh[j], smem + 2 * ACH + dB[j]);
        gload16(pBl[j], smem + 2 * ACH + 4096 + dB[j]);
    }
    __syncthreads();

    for (int t = 0; t < 16; ++t) {
        const int bo = (t & 1) * BUF;
        if (t < 15) {
            const int bn = BUF - bo;
            const int k  = (t + 1) * 64;
            #pragma unroll
            for (int j = 0; j < NAC; ++j) {
                gload16(pAh[j] + k, smem + bn + dA[j]);
                gload16(pAl[j] + k, smem + bn + ACH + dA[j]);
            }
            #pragma unroll
            for (int j = 0; j < 2; ++j) {
                gload16(pBh[j] + k, smem + bn + 2 * ACH + dB[j]);
                gload16(pBl[j] + k, smem + bn + 2 * ACH + 4096 + dB[j]);
            }
        }
        #pragma unroll
        for (int kc = 0; kc < 2; ++kc) {
            bf16x8 ah[NMI], al[NMI];
            #pragma unroll
            for (int mi = 0; mi < NMI; ++mi) {
                ah[mi] = *(const bf16x8*)(smem + bo +       afo[mi] + g16[kc]);
                al[mi] = *(const bf16x8*)(smem + bo + ACH + afo[mi] + g16[kc]);
            }
            const bf16x8 bh2 = *(const bf16x8*)(smem + bo + 2 * ACH +        bfo + g16[kc]);
            const bf16x8 bl2 = *(const bf16x8*)(smem + bo + 2 * ACH + 4096 + bfo + g16[kc]);
            #pragma unroll
            for (int mi = 0; mi < NMI; ++mi) {
                acc[mi] = __builtin_amdgcn_mfma_f32_16x16x32_bf16(ah[mi], bh2, acc[mi], 0, 0, 0);
                acc[mi] = __builtin_amdgcn_mfma_f32_16x16x32_bf16(ah[mi], bl2, acc[mi], 0, 0, 0);
                acc[mi] = __builtin_amdgcn_mfma_f32_16x16x32_bf16(al[mi], bh2, acc[mi], 0, 0, 0);
            }
        }
        __syncthreads();
    }

    // epilogue: C row = (lane>>4)*4 + r, col = lane&15 (harness-verified)
    const int col = col0 + wv * 16 + q15;
    const float bval = ldin(bias, col, F);
    #pragma unroll
    for (int mi = 0; mi < NMI; ++mi) {
        const int row0 = m0 + mi * 16 + hi4;
        if (MODE == 1) {
            #pragma unroll
            for (int r = 0; r < 4; ++r) {
                const int row = row0 + r;
                Yout[row * HIDC + col] =
                    acc[mi][r] + bval + ldin(xres, row * HIDC + col, F);
            }
        } else if (mat == 2) {
            ushort4 oh, ol;
            u16 h_, l_;
            split2(acc[mi][0] + bval, h_, l_); oh.x = h_; ol.x = l_;
            split2(acc[mi][1] + bval, h_, l_); oh.y = h_; ol.y = l_;
            split2(acc[mi][2] + bval, h_, l_); oh.z = h_; ol.z = l_;
            split2(acc[mi][3] + bval, h_, l_); oh.w = h_; ol.w = l_;
            *(ushort4*)&Vth[col * SEQ + row0] = oh;
            *(ushort4*)&Vtl[col * SEQ + row0] = ol;
        } else {
            u16* Oh = (mat == 0) ? Qh : Kh;
            u16* Ol = (mat == 0) ? Ql : Kl;
            #pragma unroll
            for (int r = 0; r < 4; ++r) {
                u16 h_, l_;
                split2(acc[mi][r] + bval, h_, l_);
                Oh[(row0 + r) * HIDC + col] = h_;
                Ol[(row0 + r) * HIDC + col] = l_;
            }
        }
    }
}

// ---------------- K2: DFT-as-MFMA + amplitude normalize + pad + split ----------------
// (round-6 verified version, verbatim)
__global__ __launch_bounds__(256) void dft_kernel(
    const u16* __restrict__ Qmh, const u16* __restrict__ Qml,
    const u16* __restrict__ Kmh, const u16* __restrict__ Kml,
    u16* __restrict__ Qsh, u16* __restrict__ Qsl,
    u16* __restrict__ Ksh, u16* __restrict__ Ksl)
{
    __shared__ __align__(16) u16 smem[16384];   // stage: Ah@0, Al@4096; then C f32[64][128]
    __shared__ float tcos[64], tsin[64];

    const int tid  = threadIdx.x;
    const int lane = tid & 63, wv = tid >> 6;
    const int hi = lane >> 4, q15 = lane & 15, l7 = lane & 7;
    const int m0  = blockIdx.x * 64;
    const int sel = blockIdx.y;
    const u16* Ah_g = sel ? Kmh : Qmh;
    const u16* Al_g = sel ? Kml : Qml;
    u16* Oh = sel ? Ksh : Qsh;
    u16* Ol = sel ? Ksl : Qsl;

    const int rsub = lane >> 3;
    const int gsw  = ((lane & 7) ^ rsub) * 8;
    #pragma unroll
    for (int j = 0; j < 2; ++j) {
        const int c = wv * 2 + j;
        gload16(Ah_g + (m0 + c * 8 + rsub) * 64 + gsw, smem + c * 512);
        gload16(Al_g + (m0 + c * 8 + rsub) * 64 + gsw, smem + 4096 + c * 512);
    }
    if (tid < 64) {
        float sv, cv;
        sincosf((float)tid * (6.283185307179586f / 64.0f), &sv, &cv);
        tcos[tid] = cv; tsin[tid] = sv;
    }
    __syncthreads();

    bf16x8 Dh[2][2], Dl[2][2];
    #pragma unroll
    for (int ni = 0; ni < 2; ++ni) {
        const int c = wv * 32 + ni * 16 + q15;
        #pragma unroll
        for (int kc = 0; kc < 2; ++kc) {
            u16x8 bh_, bl_;
            #pragma unroll
            for (int e = 0; e < 8; ++e) {
                const int k = (kc * 4 + hi) * 8 + e;
                float dv;
                if (c < 33)      dv = tcos[(c * k) & 63];
                else if (c < 66) dv = -tsin[((c - 33) * k) & 63];
                else             dv = 0.0f;
                u16 h_, l_;
                split2(dv, h_, l_);
                bh_[e] = h_; bl_[e] = l_;
            }
            Dh[ni][kc] = __builtin_bit_cast(bf16x8, bh_);
            Dl[ni][kc] = __builtin_bit_cast(bf16x8, bl_);
        }
    }

    f32x4 acc[4][2];
    #pragma unroll
    for (int mi = 0; mi < 4; ++mi)
        #pragma unroll
        for (int ni = 0; ni < 2; ++ni) acc[mi][ni] = f32x4{0.f, 0.f, 0.f, 0.f};

    #pragma unroll
    for (int kc = 0; kc < 2; ++kc) {
        const int g = (((kc * 4) + hi) ^ l7) * 8;
        bf16x8 ah[4], al[4];
        #pragma unroll
        for (int mi = 0; mi < 4; ++mi) {
            ah[mi] = *(const bf16x8*)(smem +        (mi * 16 + q15) * 64 + g);
            al[mi] = *(const bf16x8*)(smem + 4096 + (mi * 16 + q15) * 64 + g);
        }
        #pragma unroll
        for (int mi = 0; mi < 4; ++mi)
            #pragma unroll
            for (int ni = 0; ni < 2; ++ni) {
                acc[mi][ni] = __builtin_amdgcn_mfma_f32_16x16x32_bf16(
                    ah[mi], Dh[ni][kc], acc[mi][ni], 0, 0, 0);
                acc[mi][ni] = __builtin_amdgcn_mfma_f32_16x16x32_bf16(
                    ah[mi], Dl[ni][kc], acc[mi][ni], 0, 0, 0);
                acc[mi][ni] = __builtin_amdgcn_mfma_f32_16x16x32_bf16(
                    al[mi], Dh[ni][kc], acc[mi][ni], 0, 0, 0);
            }
    }
    __syncthreads();   // A reads done; reuse smem as C

    float* Cl = (float*)smem;   // [64][128]
    #pragma unroll
    for (int mi = 0; mi < 4; ++mi)
        #pragma unroll
        for (int ni = 0; ni < 2; ++ni)
            #pragma unroll
            for (int r = 0; r < 4; ++r)
                Cl[(mi * 16 + hi * 4 + r) * 128 + wv * 32 + ni * 16 + q15] = acc[mi][ni][r];
    __syncthreads();

    const int row = tid >> 2, tf = tid & 3;
    const int g   = m0 + row;
    const int ss  = g >> 4, hh = g & 15;
    u16 vh[32], vl[32];
    #pragma unroll
    for (int j = 0; j < 32; ++j) {
        const int f = tf * 32 + j;
        float val = 0.0f;
        if (f < 66) {
            const int fb = (f < 33) ? f : (f - 33);
            const float re = Cl[row * 128 + fb];
            const float im = Cl[row * 128 + 33 + fb];
            const float a  = sqrtf(re * re + im * im);
            const float sc = (a > 0.0f) ? rsqrtf(a) : 0.0f;
            val = ((f < 33) ? re : im) * sc;
        }
        split2(val, vh[j], vl[j]);
    }
    const int obase = (hh * SEQ + ss) * NFP + tf * 32;
    #pragma unroll
    for (int j4 = 0; j4 < 8; ++j4) {
        ushort4 oh, ol;
        oh.x = vh[j4 * 4 + 0]; oh.y = vh[j4 * 4 + 1]; oh.z = vh[j4 * 4 + 2]; oh.w = vh[j4 * 4 + 3];
        ol.x = vl[j4 * 4 + 0]; ol.y = vl[j4 * 4 + 1]; ol.z = vl[j4 * 4 + 2]; ol.w = vl[j4 * 4 + 3];
        *(ushort4*)&Oh[obase + j4 * 4] = oh;
        *(ushort4*)&Ol[obase + j4 * 4] = ol;
    }
}

// ---------------- K3: MFMA attention (unchanged, verified) ----------------
__global__ __launch_bounds__(128) void attn_mfma_kernel(
    const u16* __restrict__ Qsh, const u16* __restrict__ Qsl,
    const u16* __restrict__ Ksh, const u16* __restrict__ Ksl,
    const u16* __restrict__ VTh, const u16* __restrict__ VTl,
    const int* __restrict__ mask, const void* __restrict__ temp_p,
    u16* __restrict__ chi, u16* __restrict__ clo,
    const void* __restrict__ wq_sniff)
{
    __shared__ __align__(16) u16 smem[32768];   // 64 KB: wave w owns [w*16384, +16384)
    __shared__ int   mask_lds[512];
    __shared__ float mpart[2][16], lpart[2][16], l_final[16];

    const int F    = sniffF((const u16*)wq_sniff);
    const int tid  = threadIdx.x;
    const int lane = tid & 63, w = tid >> 6;
    const int hi = lane >> 4, q15 = lane & 15, l7 = lane & 7;
    const int h  = blockIdx.y, q0 = blockIdx.x * 16;
    const int k0 = w * 256;
    const int WB = w * 16384;
    const float temp = ldin(temp_p, 0, F);

    *(int4*)&mask_lds[tid * 4] = *(const int4*)&mask[tid * 4];

    bf16x8 qfh[3], qfl[3];
    {
        const int qrow = (h * SEQ + q0 + q15) * NFP;
        #pragma unroll
        for (int kc = 0; kc < 3; ++kc) {
            qfh[kc] = *(const bf16x8*)(Qsh + qrow + kc * 32 + hi * 8);
            qfl[kc] = *(const bf16x8*)(Qsl + qrow + kc * 32 + hi * 8);
        }
    }

    const int rc4 = lane >> 4;

    auto stageK = [&](int kt, int b) {
        const int base = WB + b * 8192;
        #pragma unroll
        for (int j = 0; j < 8; ++j) {
            const int row = j * 4 + rc4;
            const int gs  = (q15 ^ (row & 7)) * 8;
            const int so  = (h * SEQ + k0 + kt * 32 + row) * NFP + gs;
            gload16(Ksh + so, smem + base + j * 512);
            gload16(Ksl + so, smem + base + 4096 + j * 512);
        }
    };
    auto stageV = [&](int c, int b) {
        const int base = WB + b * 4096;
        #pragma unroll
        for (int j = 0; j < 4; ++j) {
            const int d  = j * 16 + (lane >> 2);
            const int gs = ((lane & 3) ^ (d & 3)) * 8;
            const int so = (h * HDIM + d) * SEQ + k0 + c * 32 + gs;
            gload16(VTh + so, smem + base + j * 512);
            gload16(VTl + so, smem + base + 2048 + j * 512);
        }
    };

    f32x4 sT[16];
    #pragma unroll
    for (int t = 0; t < 16; ++t) sT[t] = f32x4{0.f, 0.f, 0.f, 0.f};

    stageK(0, 0);
    #pragma unroll
    for (int kt = 0; kt < 8; ++kt) {
        if (kt < 7) {
            stageK(kt + 1, (kt + 1) & 1);
            asm volatile("s_waitcnt vmcnt(16)" ::: "memory");
        } else {
            asm volatile("s_waitcnt vmcnt(0)" ::: "memory");
        }
        __builtin_amdgcn_sched_barrier(0);
        const int base = WB + (kt & 1) * 8192;
        #pragma unroll
        for (int tt = 0; tt < 2; ++tt) {
            #pragma unroll
            for (int kc = 0; kc < 3; ++kc) {
                const int ro = (tt * 16 + q15) * 128 + (((kc * 4 + hi) ^ l7) * 8);
                const bf16x8 ah = *(const bf16x8*)(smem + base + ro);
                const bf16x8 al = *(const bf16x8*)(smem + base + 4096 + ro);
                sT[kt * 2 + tt] = __builtin_amdgcn_mfma_f32_16x16x32_bf16(ah, qfh[kc], sT[kt * 2 + tt], 0, 0, 0);
                sT[kt * 2 + tt] = __builtin_amdgcn_mfma_f32_16x16x32_bf16(ah, qfl[kc], sT[kt * 2 + tt], 0, 0, 0);
                sT[kt * 2 + tt] = __builtin_amdgcn_mfma_f32_16x16x32_bf16(al, qfh[kc], sT[kt * 2 + tt], 0, 0, 0);
            }
        }
    }

    __builtin_amdgcn_sched_barrier(0);
    stageV(0, 0);

    float m = -1e30f;
    #pragma unroll
    for (int t = 0; t < 16; ++t) {
        const int4 mv = *(const int4*)&mask_lds[k0 + t * 16 + hi * 4];
        float s;
        s = (mv.x == 0) ? -1e9f : sT[t][0] * temp; sT[t][0] = s; m = fmaxf(m, s);
        s = (mv.y == 0) ? -1e9f : sT[t][1] * temp; sT[t][1] = s; m = fmaxf(m, s);
        s = (mv.z == 0) ? -1e9f : sT[t][2] * temp; sT[t][2] = s; m = fmaxf(m, s);
        s = (mv.w == 0) ? -1e9f : sT[t][3] * temp; sT[t][3] = s; m = fmaxf(m, s);
    }
    m = fmaxf(m, __shfl_xor(m, 16, 64));
    m = fmaxf(m, __shfl_xor(m, 32, 64));
    if (lane < 16) mpart[w][q15] = m;
    __syncthreads();
    const float gm = fmaxf(mpart[0][q15], mpart[1][q15]);
    float sum = 0.0f;
    #pragma unroll
    for (int t = 0; t < 16; ++t) {
        #pragma unroll
        for (int r = 0; r < 4; ++r) {
            const float p = __expf(sT[t][r] - gm);
            sT[t][r] = p;
            sum += p;
        }
    }
    sum += __shfl_xor(sum, 16, 64);
    sum += __shfl_xor(sum, 32, 64);
    if (lane < 16) lpart[w][q15] = sum;
    __syncthreads();
    if (tid < 16) l_final[tid] = lpart[0][tid] + lpart[1][tid];

    const int PH = WB + 8192, PL = PH + 640;
    f32x4 acc[4];
    #pragma unroll
    for (int dt = 0; dt < 4; ++dt) acc[dt] = f32x4{0.f, 0.f, 0.f, 0.f};

    #pragma unroll
    for (int c = 0; c < 8; ++c) {
        if (c < 7) {
            stageV(c + 1, (c + 1) & 1);
            asm volatile("s_waitcnt vmcnt(8)" ::: "memory");
        } else {
            asm volatile("s_waitcnt vmcnt(0)" ::: "memory");
        }
        __builtin_amdgcn_sched_barrier(0);
        #pragma unroll
        for (int tt = 0; tt < 2; ++tt) {
            const int t = c * 2 + tt;
            ushort4 ph, pl;
            u16 hh, ll;
            split2(sT[t][0], hh, ll); ph.x = hh; pl.x = ll;
            split2(sT[t][1], hh, ll); ph.y = hh; pl.y = ll;
            split2(sT[t][2], hh, ll); ph.z = hh; pl.z = ll;
            split2(sT[t][3], hh, ll); ph.w = hh; pl.w = ll;
            const int g  = tt * 2 + (hi >> 1);
            const int po = q15 * 40 + ((g ^ (q15 & 3)) * 8) + (hi & 1) * 4;
            *(ushort4*)(smem + PH + po) = ph;
            *(ushort4*)(smem + PL + po) = pl;
        }
        const int vb  = WB + (c & 1) * 4096;
        const int pro = q15 * 40 + ((hi ^ (q15 & 3)) * 8);
        const bf16x8 pfh = *(const bf16x8*)(smem + PH + pro);
        const bf16x8 pfl = *(const bf16x8*)(smem + PL + pro);
        #pragma unroll
        for (int dt = 0; dt < 4; ++dt) {
            const int vo = (dt * 16 + q15) * 32 + ((hi ^ (q15 & 3)) * 8);
            const bf16x8 vfh = *(const bf16x8*)(smem + vb + vo);
            const bf16x8 vfl = *(const bf16x8*)(smem + vb + 2048 + vo);
            acc[dt] = __builtin_amdgcn_mfma_f32_16x16x32_bf16(pfh, vfh, acc[dt], 0, 0, 0);
            acc[dt] = __builtin_amdgcn_mfma_f32_16x16x32_bf16(pfl, vfh, acc[dt], 0, 0, 0);
            acc[dt] = __builtin_amdgcn_mfma_f32_16x16x32_bf16(pfh, vfl, acc[dt], 0, 0, 0);
        }
    }

    float* pacc = (float*)(smem + WB + 12288);
    #pragma unroll
    for (int dt = 0; dt < 4; ++dt)
        *(f32x4*)&pacc[(dt * 64 + lane) * 4] = acc[dt];
    __syncthreads();
    const float* pa0 = (const float*)(smem + 12288);
    const float* pa1 = (const float*)(smem + 16384 + 12288);
    #pragma unroll
    for (int dd = 0; dd < 2; ++dd) {
        const int dt = w * 2 + dd;
        #pragma unroll
        for (int r = 0; r < 4; ++r) {
            const int idx = (dt * 64 + lane) * 4 + r;
            const float v = (pa0[idx] + pa1[idx]) / l_final[hi * 4 + r];
            u16 hh, ll;
            split2(v, hh, ll);
            const int row = q0 + hi * 4 + r;
            const int col = h * HDIM + dt * 16 + q15;
            chi[row * HIDC + col] = hh;
            clo[row * HIDC + col] = ll;
        }
    }
}

// ---------------- K5: LayerNorm -> out ----------------
__global__ __launch_bounds__(256) void ln_kernel(
    const float* __restrict__ Y, const void* __restrict__ gamma,
    const void* __restrict__ beta, void* __restrict__ out,
    const void* __restrict__ wq_sniff)
{
    const int F = sniffF((const u16*)wq_sniff);
    const int row = blockIdx.x, tid = threadIdx.x;
    float v[4];
    float s = 0.0f, s2 = 0.0f;
    #pragma unroll
    for (int j = 0; j < 4; ++j) {
        v[j] = Y[row * HIDC + tid + j * 256];
        s += v[j]; s2 += v[j] * v[j];
    }
    #pragma unroll
    for (int off = 32; off > 0; off >>= 1) {
        s  += __shfl_xor(s, off, 64);
        s2 += __shfl_xor(s2, off, 64);
    }
    __shared__ float wred[4][2];
    const int w = tid >> 6;
    if ((tid & 63) == 0) { wred[w][0] = s; wred[w][1] = s2; }
    __syncthreads();
    s  = wred[0][0] + wred[1][0] + wred[2][0] + wred[3][0];
    s2 = wred[0][1] + wred[1][1] + wred[2][1] + wred[3][1];
    const float mu   = s / (float)HIDC;
    const float var  = s2 / (float)HIDC - mu * mu;
    const float rstd = rsqrtf(var + 1e-5f);
    #pragma unroll
    for (int j = 0; j < 4; ++j) {
        const int c = tid + j * 256;
        const float g = ldin(gamma, c, F), b = ldin(beta, c, F);
        const float r = (v[j] - mu) * rstd * g + b;
        if (F) ((float*)out)[row * HIDC + c] = r;
        else   ((__hip_bfloat16*)out)[row * HIDC + c] = __float2bfloat16(r);
    }
}

extern "C" void kernel_launch(void* const* d_in, const int* in_sizes, int n_in,
                              void* d_out, int out_size, void* d_ws, size_t ws_size,
                              hipStream_t stream) {
    const void* x    = d_in[0];
    const int*  mask = (const int*)d_in[1];
    const void* Wq   = d_in[2];
    const void* bq   = d_in[3];
    const void* Wk   = d_in[4];
    const void* bk   = d_in[5];
    const void* Wv   = d_in[6];
    const void* bv   = d_in[7];
    const void* Wo   = d_in[8];
    const void* bo   = d_in[9];
    const void* temp = d_in[10];
    const void* gam  = d_in[11];
    const void* bet  = d_in[12];

    float* Y    = (float*)d_ws;              // 512*1024 f32
    u16*   xhi  = (u16*)(Y + SEQ * HIDC);    // each 512*1024 u16
    u16*   xlo  = xhi + SEQ * HIDC;
    u16*   chi  = xlo + SEQ * HIDC;
    u16*   clo  = chi + SEQ * HIDC;
    u16*   Qmh  = clo + SEQ * HIDC;
    u16*   Qml  = Qmh + SEQ * HIDC;
    u16*   Kmh  = Qml + SEQ * HIDC;
    u16*   Kml  = Kmh + SEQ * HIDC;
    u16*   VTh  = Kml + SEQ * HIDC;          // [h*64+d][s]
    u16*   VTl  = VTh + NH * HDIM * SEQ;
    u16*   Wqh  = VTl + NH * HDIM * SEQ;     // 8 x 1024*1024
    u16*   Wql  = Wqh + HIDC * HIDC;
    u16*   Wkh  = Wql + HIDC * HIDC;
    u16*   Wkl  = Wkh + HIDC * HIDC;
    u16*   Wvh  = Wkl + HIDC * HIDC;
    u16*   Wvl  = Wvh + HIDC * HIDC;
    u16*   Woh  = Wvl + HIDC * HIDC;
    u16*   Wol  = Woh + HIDC * HIDC;
    u16*   Qsh  = Wol + HIDC * HIDC;         // 4 x 16*512*128
    u16*   Qsl  = Qsh + NH * SEQ * NFP;
    u16*   Ksh  = Qsl + NH * SEQ * NFP;
    u16*   Ksl  = Ksh + NH * SEQ * NFP;

    // prep: W transpose+split (z<4) + x split (z==4); dtype sniffed inline
    prep_kernel<<<dim3(16, 16, 5), 256, 0, stream>>>(
        Wq, Wk, Wv, Wo, Wqh, Wql, Wkh, Wkl, Wvh, Wvl, Woh, Wol,
        x, xhi, xlo);

    // QKV projection (N-tile 64): Q,K -> split bf16; V -> transposed split bf16
    mfma3_gemm_kernel<0, 64><<<dim3(48, 8), 256, 0, stream>>>(
        xhi, xlo, Wqh, Wql, Wkh, Wkl, Wvh, Wvl,
        bq, bk, bv, nullptr,
        Qmh, Qml, Kmh, Kml, VTh, VTl, nullptr, Wq);

    // DFT (MFMA) + normalize + pad + split -> Qs/Ks
    dft_kernel<<<dim3(128, 2), 256, 0, stream>>>(
        Qmh, Qml, Kmh, Kml, Qsh, Qsl, Ksh, Ksl);

    // attention (MFMA, k-split + counted-vmcnt dbuf), writes split ctx
    attn_mfma_kernel<<<dim3(SEQ / 16, NH), 128, 0, stream>>>(
        Qsh, Qsl, Ksh, Ksl, VTh, VTl, mask, temp, chi, clo, Wq);

    // O-projection (+bias+residual), MT=32 N-tile 64: 256 blocks, 3 blocks/CU
    mfma3_gemm_kernel<1, 32><<<dim3(16, 16), 256, 0, stream>>>(
        chi, clo, Woh, Wol, nullptr, nullptr, nullptr, nullptr,
        bo, nullptr, nullptr, x,
        nullptr, nullptr, nullptr, nullptr, nullptr, nullptr, Y, Wq);

    ln_kernel<<<SEQ, 256, 0, stream>>>(Y, gam, bet, d_out, Wq);
}

// Round 12
// 155.335 us; speedup vs baseline: 1.1162x; 1.0025x over previous
//
#include <hip/hip_runtime.h>
#include <hip/hip_bf16.h>
#include <math.h>

constexpr int SEQ   = 512;
constexpr int HIDC  = 1024;
constexpr int NH    = 16;
constexpr int HDIM  = 64;
constexpr int NFREQ = 33;   // rfft bins for n=64
constexpr int NFP   = 128;  // padded packed spectral length (66 -> 128, zero pad)

typedef unsigned short u16;
typedef __bf16 bf16x8 __attribute__((ext_vector_type(8)));
typedef float  f32x4  __attribute__((ext_vector_type(4)));
typedef unsigned short u16x8 __attribute__((ext_vector_type(8)));

typedef __attribute__((address_space(3))) void       as3_void;
typedef __attribute__((address_space(1))) const void as1_void;

// async global->LDS, 16B per lane; LDS dest = wave-uniform base + lane*16
__device__ __forceinline__ void gload16(const u16* g, u16* l) {
    __builtin_amdgcn_global_load_lds((as1_void*)g, (as3_void*)l, 16, 0, 0);
}

// dtype-agnostic input load: f32 ? float : bf16
__device__ __forceinline__ float ldin(const void* p, int i, int f32) {
    if (f32) return ((const float*)p)[i];
    return __bfloat162float(((const __hip_bfloat16*)p)[i]);
}

__device__ __forceinline__ u16 f2b(float f) {   // RNE fp32 -> bf16 bits
    unsigned int u = __builtin_bit_cast(unsigned int, f);
    u += 0x7fffu + ((u >> 16) & 1u);
    return (u16)(u >> 16);
}
__device__ __forceinline__ float b2f(u16 b) {
    return __builtin_bit_cast(float, (unsigned int)b << 16);
}
// fp32 -> (hi, lo) bf16 pair; hi + lo ~ f to ~16 mantissa bits
__device__ __forceinline__ void split2(float f, u16& hi, u16& lo) {
    hi = f2b(f);
    lo = f2b(f - b2f(hi));
}

// inline dtype sniff: wave-uniform, no barrier.
__device__ __forceinline__ int sniffF(const u16* wq) {
    const int lane = threadIdx.x & 63;
    const ushort4 a = *(const ushort4*)(wq + lane * 8);
    const ushort4 b = *(const ushort4*)(wq + lane * 8 + 4);
    int bad = 0;
    {
        const u16 vs[8] = {a.x, a.y, a.z, a.w, b.x, b.y, b.z, b.w};
        #pragma unroll
        for (int j = 0; j < 8; ++j)
            if (((vs[j] >> 7) & 0xFF) >= 134) bad++;
    }
    #pragma unroll
    for (int off = 32; off > 0; off >>= 1) bad += __shfl_xor(bad, off, 64);
    return (bad > 32) ? 1 : 0;
}

// ---------------- K1a: prep = W transpose+split (z<4) | x split (z==4) ----------------
__global__ __launch_bounds__(256) void prep_kernel(
    const void* __restrict__ W0, const void* __restrict__ W1,
    const void* __restrict__ W2, const void* __restrict__ W3,
    u16* __restrict__ H0, u16* __restrict__ L0,
    u16* __restrict__ H1, u16* __restrict__ L1,
    u16* __restrict__ H2, u16* __restrict__ L2,
    u16* __restrict__ H3, u16* __restrict__ L3,
    const void* __restrict__ xsrc, u16* __restrict__ xhi, u16* __restrict__ xlo)
{
    const int F  = sniffF((const u16*)W0);
    const int mz = blockIdx.z;

    if (mz == 4) {   // x split
        const int blk = blockIdx.y * 16 + blockIdx.x;
        const int i0  = blk * 2048 + threadIdx.x * 8;
        #pragma unroll
        for (int g = 0; g < 2; ++g) {
            const int i = i0 + g * 4;
            float v[4];
            if (F) {
                const float4 f = *(const float4*)((const float*)xsrc + i);
                v[0] = f.x; v[1] = f.y; v[2] = f.z; v[3] = f.w;
            } else {
                #pragma unroll
                for (int j = 0; j < 4; ++j) v[j] = ldin(xsrc, i + j, 0);
            }
            ushort4 oh, ol;
            u16 h, l;
            split2(v[0], h, l); oh.x = h; ol.x = l;
            split2(v[1], h, l); oh.y = h; ol.y = l;
            split2(v[2], h, l); oh.z = h; ol.z = l;
            split2(v[3], h, l); oh.w = h; ol.w = l;
            *(ushort4*)&xhi[i] = oh;
            *(ushort4*)&xlo[i] = ol;
        }
        return;
    }

    __shared__ float t[64][65];
    const void* W = (mz == 0) ? W0 : (mz == 1) ? W1 : (mz == 2) ? W2 : W3;
    u16* H = (mz == 0) ? H0 : (mz == 1) ? H1 : (mz == 2) ? H2 : H3;
    u16* L = (mz == 0) ? L0 : (mz == 1) ? L1 : (mz == 2) ? L2 : L3;
    const int n0 = blockIdx.x * 64, k0 = blockIdx.y * 64;
    const int tid = threadIdx.x;

    #pragma unroll
    for (int i = 0; i < 4; ++i) {
        const int item = i * 256 + tid;
        const int r = item >> 4, c4 = (item & 15) * 4;
        if (F) {
            const float4 v = *(const float4*)((const float*)W + (k0 + r) * HIDC + n0 + c4);
            t[r][c4 + 0] = v.x; t[r][c4 + 1] = v.y; t[r][c4 + 2] = v.z; t[r][c4 + 3] = v.w;
        } else {
            #pragma unroll
            for (int j = 0; j < 4; ++j)
                t[r][c4 + j] = ldin(W, (k0 + r) * HIDC + n0 + c4 + j, 0);
        }
    }
    __syncthreads();
    #pragma unroll
    for (int i = 0; i < 4; ++i) {
        const int item = i * 256 + tid;
        const int r = item >> 4, c4 = (item & 15) * 4;   // r: n-offset, c4: k-offset
        ushort4 oh, ol;
        u16 h, l;
        split2(t[c4 + 0][r], h, l); oh.x = h; ol.x = l;
        split2(t[c4 + 1][r], h, l); oh.y = h; ol.y = l;
        split2(t[c4 + 2][r], h, l); oh.z = h; ol.z = l;
        split2(t[c4 + 3][r], h, l); oh.w = h; ol.w = l;
        *(ushort4*)&H[(n0 + r) * HIDC + k0 + c4] = oh;
        *(ushort4*)&L[(n0 + r) * HIDC + k0 + c4] = ol;
    }
}

// ---------------- K1c: 3-term split-bf16 MFMA GEMM, N-tile 64 ----------------
// MODE 0 (MT=64): QKV; grid (48,8): bx<16 -> Q, <32 -> K, <48 -> V.
//   Q/K: split store to Qm/Km [s][1024] hi/lo. V: transposed split [h*64+d][s].
// MODE 1 (MT=32): O-proj; grid (16,16). Out: Y fp32 = acc + bias + residual.
template <int MODE, int MT>
__global__ __launch_bounds__(256) void mfma3_gemm_kernel(
    const u16* __restrict__ Ahi, const u16* __restrict__ Alo,
    const u16* __restrict__ B0h, const u16* __restrict__ B0l,
    const u16* __restrict__ B1h, const u16* __restrict__ B1l,
    const u16* __restrict__ B2h, const u16* __restrict__ B2l,
    const void* __restrict__ b0, const void* __restrict__ b1, const void* __restrict__ b2,
    const void* __restrict__ xres,
    u16* __restrict__ Qh, u16* __restrict__ Ql,
    u16* __restrict__ Kh, u16* __restrict__ Kl,
    u16* __restrict__ Vth, u16* __restrict__ Vtl,
    float* __restrict__ Yout,
    const void* __restrict__ wq_sniff)
{
    constexpr int NMI = MT / 16;        // acc row tiles
    constexpr int NAC = MT / 32;        // A chunks per wave
    constexpr int ACH = MT * 64;        // A hi region (u16)
    constexpr int BUF = 2 * ACH + 8192; // + B hi/lo (64 rows x 64)
    __shared__ __align__(16) u16 smem[2 * BUF];

    const int F    = sniffF((const u16*)wq_sniff);
    const int tid  = threadIdx.x;
    const int lane = tid & 63, wv = tid >> 6;
    const int q15 = lane & 15, hi = lane >> 4, l7 = lane & 7;
    const int hi4 = hi * 4;
    const int m0 = blockIdx.y * MT;
    const int n0 = blockIdx.x * 64;

    const u16 *Bh, *Bl; const void* bias; int col0, mat = 0;
    if (MODE == 0) {
        mat  = n0 >> 10;
        col0 = n0 & 1023;
        Bh   = (mat == 0) ? B0h : (mat == 1) ? B1h : B2h;
        Bl   = (mat == 0) ? B0l : (mat == 1) ? B1l : B2l;
        bias = (mat == 0) ? b0  : (mat == 1) ? b1  : b2;
    } else {
        col0 = n0; Bh = B0h; Bl = B0l; bias = b0;
    }

    const int rsub = lane >> 3;
    const int gsw  = ((lane & 7) ^ rsub) * 8;
    const u16* pAh[2]; const u16* pAl[2];
    const u16* pBh[2]; const u16* pBl[2];
    int dA[2], dB[2];
    #pragma unroll
    for (int j = 0; j < NAC; ++j) {
        const int c = wv * NAC + j;
        pAh[j] = Ahi + (m0 + c * 8 + rsub) * HIDC + gsw;
        pAl[j] = Alo + (m0 + c * 8 + rsub) * HIDC + gsw;
        dA[j]  = c * 512;
    }
    #pragma unroll
    for (int j = 0; j < 2; ++j) {
        const int c = wv * 2 + j;
        pBh[j] = Bh + (col0 + c * 8 + rsub) * HIDC + gsw;
        pBl[j] = Bl + (col0 + c * 8 + rsub) * HIDC + gsw;
        dB[j]  = c * 512;
    }

    int g16[2];
    #pragma unroll
    for (int kc = 0; kc < 2; ++kc) g16[kc] = (((kc * 4) + hi) ^ l7) * 8;
    int afo[4];
    #pragma unroll
    for (int mi = 0; mi < NMI; ++mi) afo[mi] = (mi * 16 + q15) * 64;
    const int bfo = (wv * 16 + q15) * 64;

    f32x4 acc[NMI];
    #pragma unroll
    for (int mi = 0; mi < NMI; ++mi) acc[mi] = f32x4{0.f, 0.f, 0.f, 0.f};

    #pragma unroll
    for (int j = 0; j < NAC; ++j) {
        gload16(pAh[j], smem + dA[j]);
        gload16(pAl[j], smem + ACH + dA[j]);
    }
    #pragma unroll
    for (int j = 0; j < 2; ++j) {
        gload16(pBh[j], smem + 2 * ACH + dB[j]);
        gload16(pBl[j], smem + 2 * ACH + 4096 + dB[j]);
    }
    __syncthreads();

    for (int t = 0; t < 16; ++t) {
        const int bo = (t & 1) * BUF;
        if (t < 15) {
            const int bn = BUF - bo;
            const int k  = (t + 1) * 64;
            #pragma unroll
            for (int j = 0; j < NAC; ++j) {
                gload16(pAh[j] + k, smem + bn + dA[j]);
                gload16(pAl[j] + k, smem + bn + ACH + dA[j]);
            }
            #pragma unroll
            for (int j = 0; j < 2; ++j) {
                gload16(pBh[j] + k, smem + bn + 2 * ACH + dB[j]);
                gload16(pBl[j] + k, smem + bn + 2 * ACH + 4096 + dB[j]);
            }
        }
        #pragma unroll
        for (int kc = 0; kc < 2; ++kc) {
            bf16x8 ah[NMI], al[NMI];
            #pragma unroll
            for (int mi = 0; mi < NMI; ++mi) {
                ah[mi] = *(const bf16x8*)(smem + bo +       afo[mi] + g16[kc]);
                al[mi] = *(const bf16x8*)(smem + bo + ACH + afo[mi] + g16[kc]);
            }
            const bf16x8 bh2 = *(const bf16x8*)(smem + bo + 2 * ACH +        bfo + g16[kc]);
            const bf16x8 bl2 = *(const bf16x8*)(smem + bo + 2 * ACH + 4096 + bfo + g16[kc]);
            #pragma unroll
            for (int mi = 0; mi < NMI; ++mi) {
                acc[mi] = __builtin_amdgcn_mfma_f32_16x16x32_bf16(ah[mi], bh2, acc[mi], 0, 0, 0);
                acc[mi] = __builtin_amdgcn_mfma_f32_16x16x32_bf16(ah[mi], bl2, acc[mi], 0, 0, 0);
                acc[mi] = __builtin_amdgcn_mfma_f32_16x16x32_bf16(al[mi], bh2, acc[mi], 0, 0, 0);
            }
        }
        __syncthreads();
    }

    // epilogue: C row = (lane>>4)*4 + r, col = lane&15 (harness-verified)
    const int col = col0 + wv * 16 + q15;
    const float bval = ldin(bias, col, F);
    #pragma unroll
    for (int mi = 0; mi < NMI; ++mi) {
        const int row0 = m0 + mi * 16 + hi4;
        if (MODE == 1) {
            #pragma unroll
            for (int r = 0; r < 4; ++r) {
                const int row = row0 + r;
                Yout[row * HIDC + col] =
                    acc[mi][r] + bval + ldin(xres, row * HIDC + col, F);
            }
        } else if (mat == 2) {
            ushort4 oh, ol;
            u16 h_, l_;
            split2(acc[mi][0] + bval, h_, l_); oh.x = h_; ol.x = l_;
            split2(acc[mi][1] + bval, h_, l_); oh.y = h_; ol.y = l_;
            split2(acc[mi][2] + bval, h_, l_); oh.z = h_; ol.z = l_;
            split2(acc[mi][3] + bval, h_, l_); oh.w = h_; ol.w = l_;
            *(ushort4*)&Vth[col * SEQ + row0] = oh;
            *(ushort4*)&Vtl[col * SEQ + row0] = ol;
        } else {
            u16* Oh = (mat == 0) ? Qh : Kh;
            u16* Ol = (mat == 0) ? Ql : Kl;
            #pragma unroll
            for (int r = 0; r < 4; ++r) {
                u16 h_, l_;
                split2(acc[mi][r] + bval, h_, l_);
                Oh[(row0 + r) * HIDC + col] = h_;
                Ol[(row0 + r) * HIDC + col] = l_;
            }
        }
    }
}

// ---------------- K2: DFT-as-MFMA + amplitude normalize + pad + split ----------------
__global__ __launch_bounds__(256) void dft_kernel(
    const u16* __restrict__ Qmh, const u16* __restrict__ Qml,
    const u16* __restrict__ Kmh, const u16* __restrict__ Kml,
    u16* __restrict__ Qsh, u16* __restrict__ Qsl,
    u16* __restrict__ Ksh, u16* __restrict__ Ksl)
{
    __shared__ __align__(16) u16 smem[16384];   // stage: Ah@0, Al@4096; then C f32[64][128]
    __shared__ float tcos[64], tsin[64];

    const int tid  = threadIdx.x;
    const int lane = tid & 63, wv = tid >> 6;
    const int hi = lane >> 4, q15 = lane & 15, l7 = lane & 7;
    const int m0  = blockIdx.x * 64;
    const int sel = blockIdx.y;
    const u16* Ah_g = sel ? Kmh : Qmh;
    const u16* Al_g = sel ? Kml : Qml;
    u16* Oh = sel ? Ksh : Qsh;
    u16* Ol = sel ? Ksl : Qsl;

    const int rsub = lane >> 3;
    const int gsw  = ((lane & 7) ^ rsub) * 8;
    #pragma unroll
    for (int j = 0; j < 2; ++j) {
        const int c = wv * 2 + j;
        gload16(Ah_g + (m0 + c * 8 + rsub) * 64 + gsw, smem + c * 512);
        gload16(Al_g + (m0 + c * 8 + rsub) * 64 + gsw, smem + 4096 + c * 512);
    }
    if (tid < 64) {
        float sv, cv;
        sincosf((float)tid * (6.283185307179586f / 64.0f), &sv, &cv);
        tcos[tid] = cv; tsin[tid] = sv;
    }
    __syncthreads();

    bf16x8 Dh[2][2], Dl[2][2];
    #pragma unroll
    for (int ni = 0; ni < 2; ++ni) {
        const int c = wv * 32 + ni * 16 + q15;
        #pragma unroll
        for (int kc = 0; kc < 2; ++kc) {
            u16x8 bh_, bl_;
            #pragma unroll
            for (int e = 0; e < 8; ++e) {
                const int k = (kc * 4 + hi) * 8 + e;
                float dv;
                if (c < 33)      dv = tcos[(c * k) & 63];
                else if (c < 66) dv = -tsin[((c - 33) * k) & 63];
                else             dv = 0.0f;
                u16 h_, l_;
                split2(dv, h_, l_);
                bh_[e] = h_; bl_[e] = l_;
            }
            Dh[ni][kc] = __builtin_bit_cast(bf16x8, bh_);
            Dl[ni][kc] = __builtin_bit_cast(bf16x8, bl_);
        }
    }

    f32x4 acc[4][2];
    #pragma unroll
    for (int mi = 0; mi < 4; ++mi)
        #pragma unroll
        for (int ni = 0; ni < 2; ++ni) acc[mi][ni] = f32x4{0.f, 0.f, 0.f, 0.f};

    #pragma unroll
    for (int kc = 0; kc < 2; ++kc) {
        const int g = (((kc * 4) + hi) ^ l7) * 8;
        bf16x8 ah[4], al[4];
        #pragma unroll
        for (int mi = 0; mi < 4; ++mi) {
            ah[mi] = *(const bf16x8*)(smem +        (mi * 16 + q15) * 64 + g);
            al[mi] = *(const bf16x8*)(smem + 4096 + (mi * 16 + q15) * 64 + g);
        }
        #pragma unroll
        for (int mi = 0; mi < 4; ++mi)
            #pragma unroll
            for (int ni = 0; ni < 2; ++ni) {
                acc[mi][ni] = __builtin_amdgcn_mfma_f32_16x16x32_bf16(
                    ah[mi], Dh[ni][kc], acc[mi][ni], 0, 0, 0);
                acc[mi][ni] = __builtin_amdgcn_mfma_f32_16x16x32_bf16(
                    ah[mi], Dl[ni][kc], acc[mi][ni], 0, 0, 0);
                acc[mi][ni] = __builtin_amdgcn_mfma_f32_16x16x32_bf16(
                    al[mi], Dh[ni][kc], acc[mi][ni], 0, 0, 0);
            }
    }
    __syncthreads();   // A reads done; reuse smem as C

    float* Cl = (float*)smem;   // [64][128]
    #pragma unroll
    for (int mi = 0; mi < 4; ++mi)
        #pragma unroll
        for (int ni = 0; ni < 2; ++ni)
            #pragma unroll
            for (int r = 0; r < 4; ++r)
                Cl[(mi * 16 + hi * 4 + r) * 128 + wv * 32 + ni * 16 + q15] = acc[mi][ni][r];
    __syncthreads();

    const int row = tid >> 2, tf = tid & 3;
    const int g   = m0 + row;
    const int ss  = g >> 4, hh = g & 15;
    u16 vh[32], vl[32];
    #pragma unroll
    for (int j = 0; j < 32; ++j) {
        const int f = tf * 32 + j;
        float val = 0.0f;
        if (f < 66) {
            const int fb = (f < 33) ? f : (f - 33);
            const float re = Cl[row * 128 + fb];
            const float im = Cl[row * 128 + 33 + fb];
            const float a  = sqrtf(re * re + im * im);
            const float sc = (a > 0.0f) ? rsqrtf(a) : 0.0f;
            val = ((f < 33) ? re : im) * sc;
        }
        split2(val, vh[j], vl[j]);
    }
    const int obase = (hh * SEQ + ss) * NFP + tf * 32;
    #pragma unroll
    for (int j4 = 0; j4 < 8; ++j4) {
        ushort4 oh, ol;
        oh.x = vh[j4 * 4 + 0]; oh.y = vh[j4 * 4 + 1]; oh.z = vh[j4 * 4 + 2]; oh.w = vh[j4 * 4 + 3];
        ol.x = vl[j4 * 4 + 0]; ol.y = vl[j4 * 4 + 1]; ol.z = vl[j4 * 4 + 2]; ol.w = vl[j4 * 4 + 3];
        *(ushort4*)&Oh[obase + j4 * 4] = oh;
        *(ushort4*)&Ol[obase + j4 * 4] = ol;
    }
}

// ---------------- K3: MFMA attention, k-split waves + counted-vmcnt dbuf ----------------
// grid (SEQ/16, NH), 128 thr. Block = 16 q-rows; wave w owns k in [w*256, w*256+256).
// Per-wave 32KB LDS region; barrier-free counted-vmcnt double-buffered staging.
// Phase 1: S^T 3-term. Softmax: 2-wave split-k reduce via LDS. Phase 2: PV 3-term.
__global__ __launch_bounds__(128) void attn_mfma_kernel(
    const u16* __restrict__ Qsh, const u16* __restrict__ Qsl,
    const u16* __restrict__ Ksh, const u16* __restrict__ Ksl,
    const u16* __restrict__ VTh, const u16* __restrict__ VTl,
    const int* __restrict__ mask, const void* __restrict__ temp_p,
    u16* __restrict__ chi, u16* __restrict__ clo,
    const void* __restrict__ wq_sniff)
{
    __shared__ __align__(16) u16 smem[32768];   // 64 KB: wave w owns [w*16384, +16384)
    __shared__ int   mask_lds[512];
    __shared__ float mpart[2][16], lpart[2][16], l_final[16];

    const int F    = sniffF((const u16*)wq_sniff);
    const int tid  = threadIdx.x;
    const int lane = tid & 63, w = tid >> 6;
    const int hi = lane >> 4, q15 = lane & 15, l7 = lane & 7;
    const int h  = blockIdx.y, q0 = blockIdx.x * 16;
    const int k0 = w * 256;
    const int WB = w * 16384;
    const float temp = ldin(temp_p, 0, F);

    *(int4*)&mask_lds[tid * 4] = *(const int4*)&mask[tid * 4];

    bf16x8 qfh[3], qfl[3];
    {
        const int qrow = (h * SEQ + q0 + q15) * NFP;
        #pragma unroll
        for (int kc = 0; kc < 3; ++kc) {
            qfh[kc] = *(const bf16x8*)(Qsh + qrow + kc * 32 + hi * 8);
            qfl[kc] = *(const bf16x8*)(Qsl + qrow + kc * 32 + hi * 8);
        }
    }

    const int rc4 = lane >> 4;

    auto stageK = [&](int kt, int b) {
        const int base = WB + b * 8192;
        #pragma unroll
        for (int j = 0; j < 8; ++j) {
            const int row = j * 4 + rc4;
            const int gs  = (q15 ^ (row & 7)) * 8;
            const int so  = (h * SEQ + k0 + kt * 32 + row) * NFP + gs;
            gload16(Ksh + so, smem + base + j * 512);
            gload16(Ksl + so, smem + base + 4096 + j * 512);
        }
    };
    auto stageV = [&](int c, int b) {
        const int base = WB + b * 4096;
        #pragma unroll
        for (int j = 0; j < 4; ++j) {
            const int d  = j * 16 + (lane >> 2);
            const int gs = ((lane & 3) ^ (d & 3)) * 8;
            const int so = (h * HDIM + d) * SEQ + k0 + c * 32 + gs;
            gload16(VTh + so, smem + base + j * 512);
            gload16(VTl + so, smem + base + 2048 + j * 512);
        }
    };

    f32x4 sT[16];
    #pragma unroll
    for (int t = 0; t < 16; ++t) sT[t] = f32x4{0.f, 0.f, 0.f, 0.f};

    stageK(0, 0);
    #pragma unroll
    for (int kt = 0; kt < 8; ++kt) {
        if (kt < 7) {
            stageK(kt + 1, (kt + 1) & 1);
            asm volatile("s_waitcnt vmcnt(16)" ::: "memory");
        } else {
            asm volatile("s_waitcnt vmcnt(0)" ::: "memory");
        }
        __builtin_amdgcn_sched_barrier(0);
        const int base = WB + (kt & 1) * 8192;
        #pragma unroll
        for (int tt = 0; tt < 2; ++tt) {
            #pragma unroll
            for (int kc = 0; kc < 3; ++kc) {
                const int ro = (tt * 16 + q15) * 128 + (((kc * 4 + hi) ^ l7) * 8);
                const bf16x8 ah = *(const bf16x8*)(smem + base + ro);
                const bf16x8 al = *(const bf16x8*)(smem + base + 4096 + ro);
                sT[kt * 2 + tt] = __builtin_amdgcn_mfma_f32_16x16x32_bf16(ah, qfh[kc], sT[kt * 2 + tt], 0, 0, 0);
                sT[kt * 2 + tt] = __builtin_amdgcn_mfma_f32_16x16x32_bf16(ah, qfl[kc], sT[kt * 2 + tt], 0, 0, 0);
                sT[kt * 2 + tt] = __builtin_amdgcn_mfma_f32_16x16x32_bf16(al, qfh[kc], sT[kt * 2 + tt], 0, 0, 0);
            }
        }
    }

    __builtin_amdgcn_sched_barrier(0);
    stageV(0, 0);

    float m = -1e30f;
    #pragma unroll
    for (int t = 0; t < 16; ++t) {
        const int4 mv = *(const int4*)&mask_lds[k0 + t * 16 + hi * 4];
        float s;
        s = (mv.x == 0) ? -1e9f : sT[t][0] * temp; sT[t][0] = s; m = fmaxf(m, s);
        s = (mv.y == 0) ? -1e9f : sT[t][1] * temp; sT[t][1] = s; m = fmaxf(m, s);
        s = (mv.z == 0) ? -1e9f : sT[t][2] * temp; sT[t][2] = s; m = fmaxf(m, s);
        s = (mv.w == 0) ? -1e9f : sT[t][3] * temp; sT[t][3] = s; m = fmaxf(m, s);
    }
    m = fmaxf(m, __shfl_xor(m, 16, 64));
    m = fmaxf(m, __shfl_xor(m, 32, 64));
    if (lane < 16) mpart[w][q15] = m;
    __syncthreads();
    const float gm = fmaxf(mpart[0][q15], mpart[1][q15]);
    float sum = 0.0f;
    #pragma unroll
    for (int t = 0; t < 16; ++t) {
        #pragma unroll
        for (int r = 0; r < 4; ++r) {
            const float p = __expf(sT[t][r] - gm);
            sT[t][r] = p;
            sum += p;
        }
    }
    sum += __shfl_xor(sum, 16, 64);
    sum += __shfl_xor(sum, 32, 64);
    if (lane < 16) lpart[w][q15] = sum;
    __syncthreads();
    if (tid < 16) l_final[tid] = lpart[0][tid] + lpart[1][tid];

    const int PH = WB + 8192, PL = PH + 640;
    f32x4 acc[4];
    #pragma unroll
    for (int dt = 0; dt < 4; ++dt) acc[dt] = f32x4{0.f, 0.f, 0.f, 0.f};

    #pragma unroll
    for (int c = 0; c < 8; ++c) {
        if (c < 7) {
            stageV(c + 1, (c + 1) & 1);
            asm volatile("s_waitcnt vmcnt(8)" ::: "memory");
        } else {
            asm volatile("s_waitcnt vmcnt(0)" ::: "memory");
        }
        __builtin_amdgcn_sched_barrier(0);
        #pragma unroll
        for (int tt = 0; tt < 2; ++tt) {
            const int t = c * 2 + tt;
            ushort4 ph, pl;
            u16 hh, ll;
            split2(sT[t][0], hh, ll); ph.x = hh; pl.x = ll;
            split2(sT[t][1], hh, ll); ph.y = hh; pl.y = ll;
            split2(sT[t][2], hh, ll); ph.z = hh; pl.z = ll;
            split2(sT[t][3], hh, ll); ph.w = hh; pl.w = ll;
            const int g  = tt * 2 + (hi >> 1);
            const int po = q15 * 40 + ((g ^ (q15 & 3)) * 8) + (hi & 1) * 4;
            *(ushort4*)(smem + PH + po) = ph;
            *(ushort4*)(smem + PL + po) = pl;
        }
        const int vb  = WB + (c & 1) * 4096;
        const int pro = q15 * 40 + ((hi ^ (q15 & 3)) * 8);
        const bf16x8 pfh = *(const bf16x8*)(smem + PH + pro);
        const bf16x8 pfl = *(const bf16x8*)(smem + PL + pro);
        #pragma unroll
        for (int dt = 0; dt < 4; ++dt) {
            const int vo = (dt * 16 + q15) * 32 + ((hi ^ (q15 & 3)) * 8);
            const bf16x8 vfh = *(const bf16x8*)(smem + vb + vo);
            const bf16x8 vfl = *(const bf16x8*)(smem + vb + 2048 + vo);
            acc[dt] = __builtin_amdgcn_mfma_f32_16x16x32_bf16(pfh, vfh, acc[dt], 0, 0, 0);
            acc[dt] = __builtin_amdgcn_mfma_f32_16x16x32_bf16(pfl, vfh, acc[dt], 0, 0, 0);
            acc[dt] = __builtin_amdgcn_mfma_f32_16x16x32_bf16(pfh, vfl, acc[dt], 0, 0, 0);
        }
    }

    float* pacc = (float*)(smem + WB + 12288);
    #pragma unroll
    for (int dt = 0; dt < 4; ++dt)
        *(f32x4*)&pacc[(dt * 64 + lane) * 4] = acc[dt];
    __syncthreads();
    const float* pa0 = (const float*)(smem + 12288);
    const float* pa1 = (const float*)(smem + 16384 + 12288);
    #pragma unroll
    for (int dd = 0; dd < 2; ++dd) {
        const int dt = w * 2 + dd;
        #pragma unroll
        for (int r = 0; r < 4; ++r) {
            const int idx = (dt * 64 + lane) * 4 + r;
            const float v = (pa0[idx] + pa1[idx]) / l_final[hi * 4 + r];
            u16 hh, ll;
            split2(v, hh, ll);
            const int row = q0 + hi * 4 + r;
            const int col = h * HDIM + dt * 16 + q15;
            chi[row * HIDC + col] = hh;
            clo[row * HIDC + col] = ll;
        }
    }
}

// ---------------- K5: LayerNorm -> out ----------------
__global__ __launch_bounds__(256) void ln_kernel(
    const float* __restrict__ Y, const void* __restrict__ gamma,
    const void* __restrict__ beta, void* __restrict__ out,
    const void* __restrict__ wq_sniff)
{
    const int F = sniffF((const u16*)wq_sniff);
    const int row = blockIdx.x, tid = threadIdx.x;
    float v[4];
    float s = 0.0f, s2 = 0.0f;
    #pragma unroll
    for (int j = 0; j < 4; ++j) {
        v[j] = Y[row * HIDC + tid + j * 256];
        s += v[j]; s2 += v[j] * v[j];
    }
    #pragma unroll
    for (int off = 32; off > 0; off >>= 1) {
        s  += __shfl_xor(s, off, 64);
        s2 += __shfl_xor(s2, off, 64);
    }
    __shared__ float wred[4][2];
    const int w = tid >> 6;
    if ((tid & 63) == 0) { wred[w][0] = s; wred[w][1] = s2; }
    __syncthreads();
    s  = wred[0][0] + wred[1][0] + wred[2][0] + wred[3][0];
    s2 = wred[0][1] + wred[1][1] + wred[2][1] + wred[3][1];
    const float mu   = s / (float)HIDC;
    const float var  = s2 / (float)HIDC - mu * mu;
    const float rstd = rsqrtf(var + 1e-5f);
    #pragma unroll
    for (int j = 0; j < 4; ++j) {
        const int c = tid + j * 256;
        const float g = ldin(gamma, c, F), b = ldin(beta, c, F);
        const float r = (v[j] - mu) * rstd * g + b;
        if (F) ((float*)out)[row * HIDC + c] = r;
        else   ((__hip_bfloat16*)out)[row * HIDC + c] = __float2bfloat16(r);
    }
}

extern "C" void kernel_launch(void* const* d_in, const int* in_sizes, int n_in,
                              void* d_out, int out_size, void* d_ws, size_t ws_size,
                              hipStream_t stream) {
    const void* x    = d_in[0];
    const int*  mask = (const int*)d_in[1];
    const void* Wq   = d_in[2];
    const void* bq   = d_in[3];
    const void* Wk   = d_in[4];
    const void* bk   = d_in[5];
    const void* Wv   = d_in[6];
    const void* bv   = d_in[7];
    const void* Wo   = d_in[8];
    const void* bo   = d_in[9];
    const void* temp = d_in[10];
    const void* gam  = d_in[11];
    const void* bet  = d_in[12];

    float* Y    = (float*)d_ws;              // 512*1024 f32
    u16*   xhi  = (u16*)(Y + SEQ * HIDC);    // each 512*1024 u16
    u16*   xlo  = xhi + SEQ * HIDC;
    u16*   chi  = xlo + SEQ * HIDC;
    u16*   clo  = chi + SEQ * HIDC;
    u16*   Qmh  = clo + SEQ * HIDC;
    u16*   Qml  = Qmh + SEQ * HIDC;
    u16*   Kmh  = Qml + SEQ * HIDC;
    u16*   Kml  = Kmh + SEQ * HIDC;
    u16*   VTh  = Kml + SEQ * HIDC;          // [h*64+d][s]
    u16*   VTl  = VTh + NH * HDIM * SEQ;
    u16*   Wqh  = VTl + NH * HDIM * SEQ;     // 8 x 1024*1024
    u16*   Wql  = Wqh + HIDC * HIDC;
    u16*   Wkh  = Wql + HIDC * HIDC;
    u16*   Wkl  = Wkh + HIDC * HIDC;
    u16*   Wvh  = Wkl + HIDC * HIDC;
    u16*   Wvl  = Wvh + HIDC * HIDC;
    u16*   Woh  = Wvl + HIDC * HIDC;
    u16*   Wol  = Woh + HIDC * HIDC;
    u16*   Qsh  = Wol + HIDC * HIDC;         // 4 x 16*512*128
    u16*   Qsl  = Qsh + NH * SEQ * NFP;
    u16*   Ksh  = Qsl + NH * SEQ * NFP;
    u16*   Ksl  = Ksh + NH * SEQ * NFP;

    // prep: W transpose+split (z<4) + x split (z==4); dtype sniffed inline
    prep_kernel<<<dim3(16, 16, 5), 256, 0, stream>>>(
        Wq, Wk, Wv, Wo, Wqh, Wql, Wkh, Wkl, Wvh, Wvl, Woh, Wol,
        x, xhi, xlo);

    // QKV projection (N-tile 64): Q,K -> split bf16; V -> transposed split bf16
    mfma3_gemm_kernel<0, 64><<<dim3(48, 8), 256, 0, stream>>>(
        xhi, xlo, Wqh, Wql, Wkh, Wkl, Wvh, Wvl,
        bq, bk, bv, nullptr,
        Qmh, Qml, Kmh, Kml, VTh, VTl, nullptr, Wq);

    // DFT (MFMA) + normalize + pad + split -> Qs/Ks
    dft_kernel<<<dim3(128, 2), 256, 0, stream>>>(
        Qmh, Qml, Kmh, Kml, Qsh, Qsl, Ksh, Ksl);

    // attention (MFMA, k-split + counted-vmcnt dbuf), writes split ctx
    attn_mfma_kernel<<<dim3(SEQ / 16, NH), 128, 0, stream>>>(
        Qsh, Qsl, Ksh, Ksl, VTh, VTl, mask, temp, chi, clo, Wq);

    // O-projection (+bias+residual), MT=32 N-tile 64: 256 blocks, 3 blocks/CU
    mfma3_gemm_kernel<1, 32><<<dim3(16, 16), 256, 0, stream>>>(
        chi, clo, Woh, Wol, nullptr, nullptr, nullptr, nullptr,
        bo, nullptr, nullptr, x,
        nullptr, nullptr, nullptr, nullptr, nullptr, nullptr, Y, Wq);

    ln_kernel<<<SEQ, 256, 0, stream>>>(Y, gam, bet, d_out, Wq);
}